// Round 4
// baseline (2364.962 us; speedup 1.0000x reference)
//
#include <hip/hip_runtime.h>
#include <hip/hip_bf16.h>

// Problem constants (fixed by the reference)
#define T_  2048
#define D_  1024
#define FF_ 512
#define E_  16
#define K_  4
#define L_  3
static constexpr float EPS   = 1e-5f;
static constexpr float SCALE = 1.0f;

// dense GEMM tile config
#define BM 64
#define BN 64
#define BK 16

// fused-MoE tile config
#define MBM 32

typedef __hip_bfloat16 bf16;

__device__ __forceinline__ float b2f(bf16 x) { return __bfloat162float(x); }

// ---------------- zero-init out0 accumulator + counters ----------------
__global__ __launch_bounds__(256) void k_zero(float* __restrict__ out0, int* __restrict__ cnt) {
    size_t i = (size_t)blockIdx.x * 256 + threadIdx.x;
    if (i < (size_t)T_ * D_) out0[i] = 0.f;
    if (blockIdx.x == 0 && threadIdx.x < 64) cnt[threadIdx.x] = 0;
}

// ---------------- block reduction ----------------
__device__ __forceinline__ float blockReduceSum(float v) {
    #pragma unroll
    for (int off = 32; off > 0; off >>= 1) v += __shfl_down(v, off, 64);
    __shared__ float s[4];
    __shared__ float tot;
    int lane = threadIdx.x & 63, wid = threadIdx.x >> 6;
    if (lane == 0) s[wid] = v;
    __syncthreads();
    if (threadIdx.x == 0) tot = s[0] + s[1] + s[2] + s[3];
    __syncthreads();
    return tot;
}

// ---------------- kernel 1: h1(bf16), res1(bf16) = addnorm(hidden, residual, op_w) ----------------
__global__ __launch_bounds__(256) void k_addnorm1(const float* __restrict__ x,
                                                  const float* __restrict__ r,
                                                  const float* __restrict__ w,
                                                  bf16* __restrict__ h,
                                                  bf16* __restrict__ res) {
    int t = blockIdx.x, tid = threadIdx.x;
    float v[4]; float ss = 0.f;
    #pragma unroll
    for (int i = 0; i < 4; i++) {
        int d = tid + 256 * i;
        float s = x[(size_t)t * D_ + d] + r[(size_t)t * D_ + d];
        v[i] = s; ss += s * s;
    }
    float tot = blockReduceSum(ss);
    float rs = rsqrtf(tot / (float)D_ + EPS);
    #pragma unroll
    for (int i = 0; i < 4; i++) {
        int d = tid + 256 * i;
        res[(size_t)t * D_ + d] = __float2bfloat16(v[i]);
        h[(size_t)t * D_ + d]   = __float2bfloat16(v[i] * rs * w[d]);
    }
}

// ---------------- kernel 1b: h2(bf16) = addnorm(y, res1, ffn_w); res_out(f32) = y+res1 ----------------
__global__ __launch_bounds__(256) void k_addnorm2(const bf16* __restrict__ y,
                                                  const bf16* __restrict__ res1,
                                                  const float* __restrict__ w,
                                                  bf16* __restrict__ h2,
                                                  float* __restrict__ res_out) {
    int t = blockIdx.x, tid = threadIdx.x;
    float v[4]; float ss = 0.f;
    #pragma unroll
    for (int i = 0; i < 4; i++) {
        int d = tid + 256 * i;
        float s = b2f(y[(size_t)t * D_ + d]) + b2f(res1[(size_t)t * D_ + d]);
        v[i] = s; ss += s * s;
    }
    float tot = blockReduceSum(ss);
    float rs = rsqrtf(tot / (float)D_ + EPS);
    #pragma unroll
    for (int i = 0; i < 4; i++) {
        int d = tid + 256 * i;
        res_out[(size_t)t * D_ + d] = v[i];
        h2[(size_t)t * D_ + d]      = __float2bfloat16(v[i] * rs * w[d]);
    }
}

// ---------------- tiled GEMM: C[M,N](bf16) = A[M,K](bf16) @ B[N,K]^T(f32) ----------------
__global__ __launch_bounds__(256) void k_gemm(const bf16* __restrict__ A,
                                              const float* __restrict__ B,
                                              bf16* __restrict__ C,
                                              int M, int N, int Kd) {
    __shared__ float As[BK][BM + 4];
    __shared__ float Bs[BK][BN + 4];
    int n0 = blockIdx.x * BN, m0 = blockIdx.y * BM;
    int tid = threadIdx.x, tx = tid & 15, ty = tid >> 4;
    float acc[4][4] = {};
    for (int kt = 0; kt < Kd; kt += BK) {
        #pragma unroll
        for (int p = 0; p < 4; p++) {
            int idx = tid + 256 * p, row = idx >> 4, kk = idx & 15;
            As[kk][row] = b2f(A[(size_t)(m0 + row) * Kd + kt + kk]);
            Bs[kk][row] = B[(size_t)(n0 + row) * Kd + kt + kk];
        }
        __syncthreads();
        #pragma unroll
        for (int k = 0; k < BK; k++) {
            float a[4], b[4];
            #pragma unroll
            for (int i = 0; i < 4; i++) a[i] = As[k][ty * 4 + i];
            #pragma unroll
            for (int j = 0; j < 4; j++) b[j] = Bs[k][tx * 4 + j];
            #pragma unroll
            for (int i = 0; i < 4; i++)
                #pragma unroll
                for (int j = 0; j < 4; j++) acc[i][j] += a[i] * b[j];
        }
        __syncthreads();
    }
    #pragma unroll
    for (int i = 0; i < 4; i++)
        #pragma unroll
        for (int j = 0; j < 4; j++)
            C[(size_t)(m0 + ty * 4 + i) * N + n0 + tx * 4 + j] = __float2bfloat16(acc[i][j]);
}

// ---------------- conv: cc[t,d] = C[t,d] * sum_l Bx[t+l-2,d]*cw[d,l] ----------------
__global__ __launch_bounds__(256) void k_conv(const bf16* __restrict__ bcx,
                                              const float* __restrict__ cw,
                                              bf16* __restrict__ cc) {
    int t = blockIdx.x, tid = threadIdx.x;
    #pragma unroll
    for (int i = 0; i < 4; i++) {
        int d = tid + 256 * i;
        float acc = 0.f;
        #pragma unroll
        for (int l = 0; l < L_; l++) {
            int tt = t + l - (L_ - 1);
            if (tt >= 0) {
                float bb = b2f(bcx[(size_t)tt * 3 * D_ + d]);
                float xx = b2f(bcx[(size_t)tt * 3 * D_ + 2 * D_ + d]);
                acc += bb * xx * cw[d * L_ + l];
            }
        }
        float c = b2f(bcx[(size_t)t * 3 * D_ + D_ + d]);
        cc[(size_t)t * D_ + d] = __float2bfloat16(c * acc);
    }
}

// ---------------- gate: sigmoid scores, biased top-4, renormalized weights, scatter ----------------
__global__ __launch_bounds__(256) void k_gate(const bf16* __restrict__ h2,
                                              const float* __restrict__ gw,
                                              const float* __restrict__ gb,
                                              int* __restrict__ cnt,
                                              int* __restrict__ tok_list,
                                              float* __restrict__ tok_w) {
    int t = blockIdx.x, tid = threadIdx.x;
    __shared__ float hs[D_];
    __shared__ float logits[E_];
    #pragma unroll
    for (int i = 0; i < 4; i++) { int d = tid + 256 * i; hs[d] = b2f(h2[(size_t)t * D_ + d]); }
    __syncthreads();
    int e = tid >> 4, j = tid & 15;
    float p = 0.f;
    for (int d = j; d < D_; d += 16) p += hs[d] * gw[(size_t)e * D_ + d];
    #pragma unroll
    for (int off = 8; off > 0; off >>= 1) p += __shfl_down(p, off, 64);
    if (j == 0) logits[e] = p;
    __syncthreads();
    if (tid == 0) {
        float sc[E_], ch[E_];
        #pragma unroll
        for (int i = 0; i < E_; i++) {
            float s = 1.f / (1.f + __expf(-logits[i]));
            sc[i] = s; ch[i] = s + gb[i];
        }
        int idx[K_]; float wv[K_]; float wsum = 0.f;
        bool used[E_] = {};
        #pragma unroll
        for (int k = 0; k < K_; k++) {
            int best = 0; float bv = -1e30f;
            for (int i = 0; i < E_; i++)
                if (!used[i] && ch[i] > bv) { bv = ch[i]; best = i; }
            used[best] = true; idx[k] = best; wv[k] = sc[best]; wsum += sc[best];
        }
        float inv = 1.f / (wsum + 1e-20f);
        for (int k = 0; k < K_; k++) {
            int eo = idx[k];
            int pos = atomicAdd(&cnt[eo], 1);
            if (pos < T_) {
                tok_list[eo * T_ + pos] = t;
                tok_w[eo * T_ + pos]    = wv[k] * inv;
            }
        }
    }
}

// ---------------- fused MoE: act tile in LDS; w1 (silu*mul) then w2 + weighted atomic combine ----
__global__ __launch_bounds__(256) void k_moe_fused(const bf16* __restrict__ h2,
                                                   const float* __restrict__ w1,
                                                   const float* __restrict__ w2,
                                                   const int* __restrict__ cnt,
                                                   const int* __restrict__ tok_list,
                                                   const float* __restrict__ tok_w,
                                                   float* __restrict__ outacc) {
    int e  = blockIdx.x >> 6;                 // T_/MBM = 64 tiles per expert
    int m0 = (blockIdx.x & 63) * MBM;
    int nt = min(cnt[e], T_);
    if (m0 >= nt) return;

    __shared__ float As[BK][MBM + 4];
    __shared__ float Bg[BK][BN + 4];
    __shared__ float Bu[BK][BN + 4];
    __shared__ bf16  act_s[MBM][FF_ + 4];     // 33 KB
    __shared__ int   toks[MBM];

    int tid = threadIdx.x, tx = tid & 15, ty = tid >> 4;
    if (tid < MBM) {
        int m = m0 + tid;
        toks[tid] = ((m < nt) ? tok_list[e * T_ + m] : tok_list[e * T_]) & (T_ - 1);
    }
    __syncthreads();

    const float* w1e = w1 + (size_t)e * 2 * FF_ * D_;
    const float* w2e = w2 + (size_t)e * D_ * FF_;

    // ---- phase 1: act = silu(h2g @ Wg^T) * (h2g @ Wu^T) into LDS ----
    for (int n0 = 0; n0 < FF_; n0 += BN) {
        float accg[2][4] = {}, accu[2][4] = {};
        for (int kt = 0; kt < D_; kt += BK) {
            #pragma unroll
            for (int p = 0; p < 2; p++) {
                int idx = tid + 256 * p, row = idx >> 4, kk = idx & 15;
                As[kk][row] = b2f(h2[(size_t)toks[row] * D_ + kt + kk]);
            }
            #pragma unroll
            for (int p = 0; p < 4; p++) {
                int idx = tid + 256 * p, row = idx >> 4, kk = idx & 15;
                Bg[kk][row] = w1e[(size_t)(n0 + row) * D_ + kt + kk];
                Bu[kk][row] = w1e[(size_t)(FF_ + n0 + row) * D_ + kt + kk];
            }
            __syncthreads();
            #pragma unroll
            for (int k = 0; k < BK; k++) {
                float a[2], bg[4], bu[4];
                #pragma unroll
                for (int i = 0; i < 2; i++) a[i] = As[k][ty * 2 + i];
                #pragma unroll
                for (int j = 0; j < 4; j++) { bg[j] = Bg[k][tx * 4 + j]; bu[j] = Bu[k][tx * 4 + j]; }
                #pragma unroll
                for (int i = 0; i < 2; i++)
                    #pragma unroll
                    for (int j = 0; j < 4; j++) {
                        accg[i][j] += a[i] * bg[j];
                        accu[i][j] += a[i] * bu[j];
                    }
            }
            __syncthreads();
        }
        #pragma unroll
        for (int i = 0; i < 2; i++)
            #pragma unroll
            for (int j = 0; j < 4; j++) {
                float g = accg[i][j], u = accu[i][j];
                float a = (g / (1.f + __expf(-g))) * u;      // silu(g)*u
                act_s[ty * 2 + i][n0 + tx * 4 + j] = __float2bfloat16(a);
            }
    }
    __syncthreads();   // act_s complete

    // ---- phase 2: out_tile = act @ W2^T, weighted atomic combine ----
    for (int n0 = 0; n0 < D_; n0 += BN) {
        float acc[2][4] = {};
        for (int kt = 0; kt < FF_; kt += BK) {
            #pragma unroll
            for (int p = 0; p < 4; p++) {
                int idx = tid + 256 * p, row = idx >> 4, kk = idx & 15;
                Bg[kk][row] = w2e[(size_t)(n0 + row) * FF_ + kt + kk];
            }
            __syncthreads();
            #pragma unroll
            for (int k = 0; k < BK; k++) {
                float a[2], b[4];
                #pragma unroll
                for (int i = 0; i < 2; i++) a[i] = b2f(act_s[ty * 2 + i][kt + k]);
                #pragma unroll
                for (int j = 0; j < 4; j++) b[j] = Bg[k][tx * 4 + j];
                #pragma unroll
                for (int i = 0; i < 2; i++)
                    #pragma unroll
                    for (int j = 0; j < 4; j++) acc[i][j] += a[i] * b[j];
            }
            __syncthreads();
        }
        #pragma unroll
        for (int i = 0; i < 2; i++) {
            int m = m0 + ty * 2 + i;
            if (m < nt) {
                float wgt = tok_w[e * T_ + m] * SCALE;
                int   tok = toks[ty * 2 + i];
                #pragma unroll
                for (int j = 0; j < 4; j++)
                    atomicAdd(&outacc[(size_t)tok * D_ + n0 + tx * 4 + j], wgt * acc[i][j]);
            }
        }
    }
}

extern "C" void kernel_launch(void* const* d_in, const int* in_sizes, int n_in,
                              void* d_out, int out_size, void* d_ws, size_t ws_size,
                              hipStream_t stream) {
    const float* hidden     = (const float*)d_in[0];
    const float* residual   = (const float*)d_in[1];
    const float* op_norm_w  = (const float*)d_in[2];
    const float* ffn_norm_w = (const float*)d_in[3];
    const float* in_proj_w  = (const float*)d_in[4];
    const float* conv_w     = (const float*)d_in[5];
    const float* out_proj_w = (const float*)d_in[6];
    const float* gate_w     = (const float*)d_in[7];
    const float* gate_bias  = (const float*)d_in[8];
    const float* w1         = (const float*)d_in[9];
    const float* w2         = (const float*)d_in[10];

    // ---- workspace: ~21 MB total ----
    char* p = (char*)d_ws;
    int*   cnt      = (int*)p;          p += 256;
    int*   tok_list = (int*)p;          p += (size_t)E_ * T_ * 4;   // 128 KB
    float* tok_w    = (float*)p;        p += (size_t)E_ * T_ * 4;   // 128 KB
    bf16*  res1     = (bf16*)p;         p += (size_t)T_ * D_ * 2;   // 4 MB
    bf16*  h1       = (bf16*)p;                                      // 4 MB (cc overlays)
    bf16*  cc       = h1;               p += (size_t)T_ * D_ * 2;
    bf16*  bcx      = (bf16*)p;                                      // 12 MB
    bf16*  y        = bcx;                                           //   y over bcx[0:4MB) (dead)
    bf16*  h2       = bcx + (size_t)T_ * D_;                         //   h2 over bcx[4:8MB) (dead)
                                        p += (size_t)T_ * 3 * D_ * 2;

    float* out0    = (float*)d_out;                   // MoE output [T,D], atomically accumulated
    float* res_out = out0 + (size_t)T_ * D_;          // residual   [T,D]

    k_zero<<<(T_ * D_ + 255) / 256, 256, 0, stream>>>(out0, cnt);
    k_addnorm1<<<T_, 256, 0, stream>>>(hidden, residual, op_norm_w, h1, res1);
    k_gemm<<<dim3(3 * D_ / BN, T_ / BM), 256, 0, stream>>>(h1, in_proj_w, bcx, T_, 3 * D_, D_);
    k_conv<<<T_, 256, 0, stream>>>(bcx, conv_w, cc);
    k_gemm<<<dim3(D_ / BN, T_ / BM), 256, 0, stream>>>(cc, out_proj_w, y, T_, D_, D_);
    k_addnorm2<<<T_, 256, 0, stream>>>(y, res1, ffn_norm_w, h2, res_out);
    k_gate<<<T_, 256, 0, stream>>>(h2, gate_w, gate_bias, cnt, tok_list, tok_w);
    k_moe_fused<<<E_ * (T_ / MBM), 256, 0, stream>>>(h2, w1, w2, cnt, tok_list, tok_w, out0);
}

// Round 6
// 553.994 us; speedup vs baseline: 4.2689x; 4.2689x over previous
//
#include <hip/hip_runtime.h>
#include <hip/hip_bf16.h>

// Problem constants (fixed by the reference)
#define T_  2048
#define D_  1024
#define FF_ 512
#define E_  16
#define K_  4
#define L_  3
static constexpr float EPS = 1e-5f;

typedef __hip_bfloat16 bf16;
typedef __attribute__((ext_vector_type(8))) short bf16x8;   // MFMA A/B frag (4 VGPRs)
typedef __attribute__((ext_vector_type(4))) float f32x4;    // MFMA C/D frag

__device__ __forceinline__ float b2f(bf16 x) { return __bfloat162float(x); }

__device__ __forceinline__ unsigned int pk2(float a, float b) {
    __hip_bfloat162 h = __float22bfloat162_rn(make_float2(a, b));
    unsigned int u; __builtin_memcpy(&u, &h, 4); return u;
}

// split f32x4 into bf16 hi + bf16 lo packed pairs (hi+lo ~ f32 precision)
__device__ __forceinline__ void split_pack(float4 v, uint2 &hi, uint2 &lo) {
    __hip_bfloat162 h01 = __float22bfloat162_rn(make_float2(v.x, v.y));
    __hip_bfloat162 h23 = __float22bfloat162_rn(make_float2(v.z, v.w));
    float2 r01 = make_float2(v.x - __bfloat162float(h01.x), v.y - __bfloat162float(h01.y));
    float2 r23 = make_float2(v.z - __bfloat162float(h23.x), v.w - __bfloat162float(h23.y));
    __hip_bfloat162 l01 = __float22bfloat162_rn(r01);
    __hip_bfloat162 l23 = __float22bfloat162_rn(r23);
    __builtin_memcpy(&hi.x, &h01, 4); __builtin_memcpy(&hi.y, &h23, 4);
    __builtin_memcpy(&lo.x, &l01, 4); __builtin_memcpy(&lo.y, &l23, 4);
}

// ---------------- zero out0 accumulator + counters ----------------
__global__ __launch_bounds__(256) void k_zero(float* __restrict__ out0, int* __restrict__ cnt) {
    size_t i = (size_t)blockIdx.x * 256 + threadIdx.x;
    if (i < (size_t)T_ * D_) out0[i] = 0.f;
    if (blockIdx.x == 0 && threadIdx.x < 64) cnt[threadIdx.x] = 0;
}

// ---------------- block reduction ----------------
__device__ __forceinline__ float blockReduceSum(float v) {
    #pragma unroll
    for (int off = 32; off > 0; off >>= 1) v += __shfl_down(v, off, 64);
    __shared__ float s[4];
    __shared__ float tot;
    int lane = threadIdx.x & 63, wid = threadIdx.x >> 6;
    if (lane == 0) s[wid] = v;
    __syncthreads();
    if (threadIdx.x == 0) tot = s[0] + s[1] + s[2] + s[3];
    __syncthreads();
    return tot;
}

// ---------------- addnorm1: h1 (hi/lo bf16) = rmsnorm(x+r)*w; res1(f32) = x+r ----------------
__global__ __launch_bounds__(256) void k_addnorm1(const float* __restrict__ x,
                                                  const float* __restrict__ r,
                                                  const float* __restrict__ w,
                                                  bf16* __restrict__ hhi,
                                                  bf16* __restrict__ hlo,
                                                  float* __restrict__ res) {
    int t = blockIdx.x, tid = threadIdx.x;
    float v[4]; float ss = 0.f;
    #pragma unroll
    for (int i = 0; i < 4; i++) {
        int d = tid + 256 * i;
        float s = x[(size_t)t * D_ + d] + r[(size_t)t * D_ + d];
        v[i] = s; ss += s * s;
    }
    float tot = blockReduceSum(ss);
    float rs = rsqrtf(tot / (float)D_ + EPS);
    #pragma unroll
    for (int i = 0; i < 4; i++) {
        int d = tid + 256 * i;
        res[(size_t)t * D_ + d] = v[i];
        float val = v[i] * rs * w[d];
        bf16 hi = __float2bfloat16(val);
        hhi[(size_t)t * D_ + d] = hi;
        hlo[(size_t)t * D_ + d] = __float2bfloat16(val - b2f(hi));
    }
}

// ---------------- addnorm2: h2(f32)+h2b(bf16) = rmsnorm(y+res)*w; res (in-place f32) = y+res ----
__global__ __launch_bounds__(256) void k_addnorm2(const float* __restrict__ y,
                                                  float* __restrict__ res,    // in-place update
                                                  const float* __restrict__ w,
                                                  float* __restrict__ h2,
                                                  bf16* __restrict__ h2b) {
    int t = blockIdx.x, tid = threadIdx.x;
    float v[4]; float ss = 0.f;
    #pragma unroll
    for (int i = 0; i < 4; i++) {
        int d = tid + 256 * i;
        float s = y[(size_t)t * D_ + d] + res[(size_t)t * D_ + d];
        v[i] = s; ss += s * s;
    }
    float tot = blockReduceSum(ss);
    float rs = rsqrtf(tot / (float)D_ + EPS);
    #pragma unroll
    for (int i = 0; i < 4; i++) {
        int d = tid + 256 * i;
        res[(size_t)t * D_ + d] = v[i];
        float val = v[i] * rs * w[d];
        h2[(size_t)t * D_ + d]  = val;
        h2b[(size_t)t * D_ + d] = __float2bfloat16(val);
    }
}

// ---------------- split-precision MFMA GEMM: C(f32)[M,N] = (Ah+Al)[M,K] @ (B f32)[N,K]^T ------
// 128x128 tile, BK=32, 4 waves x (64x64), 3-term split accumulation.
__global__ __launch_bounds__(256) void k_gemm_split(const bf16* __restrict__ Ah,
                                                    const bf16* __restrict__ Al,
                                                    const float* __restrict__ B,
                                                    float* __restrict__ C,
                                                    int M, int N, int K) {
    __shared__ bf16 Ash[128][40];
    __shared__ bf16 Asl[128][40];
    __shared__ bf16 Bsh[128][40];
    __shared__ bf16 Bsl[128][40];
    int m0 = blockIdx.y * 128, n0 = blockIdx.x * 128;
    int tid = threadIdx.x;
    int wave = tid >> 6, lane = tid & 63, ml = lane & 15, quad = lane >> 4;
    int wm = (wave >> 1) * 64, wn = (wave & 1) * 64;
    f32x4 acc[4][4] = {};
    for (int kt = 0; kt < K; kt += 32) {
        #pragma unroll
        for (int p = 0; p < 2; p++) {
            int ch = p * 256 + tid, row = ch >> 2, c8 = (ch & 3) << 3;
            *(uint4*)&Ash[row][c8] = *(const uint4*)&Ah[(size_t)(m0 + row) * K + kt + c8];
            *(uint4*)&Asl[row][c8] = *(const uint4*)&Al[(size_t)(m0 + row) * K + kt + c8];
        }
        #pragma unroll
        for (int p = 0; p < 4; p++) {
            int ch = p * 256 + tid, row = ch >> 3, c4 = (ch & 7) << 2;
            float4 v = *(const float4*)&B[(size_t)(n0 + row) * K + kt + c4];
            uint2 hi, lo; split_pack(v, hi, lo);
            *(uint2*)&Bsh[row][c4] = hi;
            *(uint2*)&Bsl[row][c4] = lo;
        }
        __syncthreads();
        bf16x8 ah[4], al[4], bh[4], bl[4];
        #pragma unroll
        for (int i = 0; i < 4; i++) {
            ah[i] = *(const bf16x8*)&Ash[wm + i * 16 + ml][quad * 8];
            al[i] = *(const bf16x8*)&Asl[wm + i * 16 + ml][quad * 8];
        }
        #pragma unroll
        for (int j = 0; j < 4; j++) {
            bh[j] = *(const bf16x8*)&Bsh[wn + j * 16 + ml][quad * 8];
            bl[j] = *(const bf16x8*)&Bsl[wn + j * 16 + ml][quad * 8];
        }
        #pragma unroll
        for (int i = 0; i < 4; i++)
            #pragma unroll
            for (int j = 0; j < 4; j++) {
                acc[i][j] = __builtin_amdgcn_mfma_f32_16x16x32_bf16(ah[i], bh[j], acc[i][j], 0, 0, 0);
                acc[i][j] = __builtin_amdgcn_mfma_f32_16x16x32_bf16(al[i], bh[j], acc[i][j], 0, 0, 0);
                acc[i][j] = __builtin_amdgcn_mfma_f32_16x16x32_bf16(ah[i], bl[j], acc[i][j], 0, 0, 0);
            }
        __syncthreads();
    }
    #pragma unroll
    for (int i = 0; i < 4; i++)
        #pragma unroll
        for (int j = 0; j < 4; j++)
            #pragma unroll
            for (int r = 0; r < 4; r++) {
                int row = m0 + wm + i * 16 + quad * 4 + r;   // C/D: row = quad*4+reg
                int col = n0 + wn + j * 16 + ml;             //      col = lane&15
                C[(size_t)row * N + col] = acc[i][j][r];
            }
}

// ---------------- conv (f32 in, hi/lo bf16 out): cc = C * sum_l Bx[t+l-2]*cw[:,l] ----------------
__global__ __launch_bounds__(256) void k_conv(const float* __restrict__ bcx,
                                              const float* __restrict__ cw,
                                              bf16* __restrict__ cchi,
                                              bf16* __restrict__ cclo) {
    int t = blockIdx.x, tid = threadIdx.x;
    #pragma unroll
    for (int i = 0; i < 4; i++) {
        int d = tid + 256 * i;
        float acc = 0.f;
        #pragma unroll
        for (int l = 0; l < L_; l++) {
            int tt = t + l - (L_ - 1);
            if (tt >= 0) {
                float bb = bcx[(size_t)tt * 3 * D_ + d];
                float xx = bcx[(size_t)tt * 3 * D_ + 2 * D_ + d];
                acc += bb * xx * cw[d * L_ + l];
            }
        }
        float c = bcx[(size_t)t * 3 * D_ + D_ + d];
        float val = c * acc;
        bf16 hi = __float2bfloat16(val);
        cchi[(size_t)t * D_ + d] = hi;
        cclo[(size_t)t * D_ + d] = __float2bfloat16(val - b2f(hi));
    }
}

// ---------------- gate (f32 h2): sigmoid scores, biased top-4, renormalize, scatter ----------------
__global__ __launch_bounds__(256) void k_gate(const float* __restrict__ h2,
                                              const float* __restrict__ gw,
                                              const float* __restrict__ gb,
                                              int* __restrict__ cnt,
                                              int* __restrict__ tok_list,
                                              float* __restrict__ tok_w) {
    int t = blockIdx.x, tid = threadIdx.x;
    __shared__ float hs[D_];
    __shared__ float logits[E_];
    #pragma unroll
    for (int i = 0; i < 4; i++) { int d = tid + 256 * i; hs[d] = h2[(size_t)t * D_ + d]; }
    __syncthreads();
    int e = tid >> 4, j = tid & 15;
    float p = 0.f;
    for (int d = j; d < D_; d += 16) p += hs[d] * gw[(size_t)e * D_ + d];
    #pragma unroll
    for (int off = 8; off > 0; off >>= 1) p += __shfl_down(p, off, 64);
    if (j == 0) logits[e] = p;
    __syncthreads();
    if (tid == 0) {
        float sc[E_], ch[E_];
        #pragma unroll
        for (int i = 0; i < E_; i++) {
            float s = 1.f / (1.f + expf(-logits[i]));
            sc[i] = s; ch[i] = s + gb[i];
        }
        int idx[K_]; float wv[K_]; float wsum = 0.f;
        bool used[E_] = {};
        #pragma unroll
        for (int k = 0; k < K_; k++) {
            int best = 0; float bv = -1e30f;
            for (int i = 0; i < E_; i++)
                if (!used[i] && ch[i] > bv) { bv = ch[i]; best = i; }
            used[best] = true; idx[k] = best; wv[k] = sc[best]; wsum += sc[best];
        }
        float inv = 1.f / (wsum + 1e-20f);
        for (int k = 0; k < K_; k++) {
            int eo = idx[k];
            int pos = atomicAdd(&cnt[eo], 1);
            if (pos < T_) {
                tok_list[eo * T_ + pos] = t;
                tok_w[eo * T_ + pos]    = wv[k] * inv;
            }
        }
    }
}

// ---------------- exclusive prefix sum over expert counts ----------------
__global__ void k_scan(const int* __restrict__ cnt, int* __restrict__ off) {
    if (threadIdx.x == 0) {
        int s = 0;
        for (int e = 0; e < E_; e++) { off[e] = s; s += min(cnt[e], T_); }
        off[E_] = s;
    }
}

// ---------------- MoE w1 (MFMA): act[base+m][n] = silu(g)*u over gathered token rows --------
__global__ __launch_bounds__(256) void k_moe_w1(const bf16* __restrict__ h2,
                                                const float* __restrict__ w1,
                                                const int* __restrict__ cnt,
                                                const int* __restrict__ off,
                                                const int* __restrict__ tok_list,
                                                bf16* __restrict__ act) {
    int e = blockIdx.y >> 4, mt = blockIdx.y & 15;
    int m0 = mt * 128;
    int nt = min(cnt[e], T_);
    if (m0 >= nt) return;
    int n0 = blockIdx.x * 64;
    int base = off[e];
    __shared__ bf16 As[128][40];
    __shared__ bf16 Bg[64][40];
    __shared__ bf16 Bu[64][40];
    __shared__ int  toks[128];
    int tid = threadIdx.x;
    if (tid < 128) {
        int m = m0 + tid;
        toks[tid] = ((m < nt) ? tok_list[e * T_ + m] : tok_list[e * T_]) & (T_ - 1);
    }
    __syncthreads();
    const float* w1e = w1 + (size_t)e * 2 * FF_ * D_;
    int wave = tid >> 6, lane = tid & 63, ml = lane & 15, quad = lane >> 4;
    int wm = wave * 32;
    f32x4 ag[2][4] = {}, au[2][4] = {};
    for (int kt = 0; kt < D_; kt += 32) {
        #pragma unroll
        for (int p = 0; p < 2; p++) {
            int ch = p * 256 + tid, row = ch >> 2, c8 = (ch & 3) << 3;
            *(uint4*)&As[row][c8] = *(const uint4*)&h2[(size_t)toks[row] * D_ + kt + c8];
        }
        #pragma unroll
        for (int p = 0; p < 2; p++) {
            int ch = p * 256 + tid, row = ch >> 3, c4 = (ch & 7) << 2;
            float4 vg = *(const float4*)&w1e[(size_t)(n0 + row) * D_ + kt + c4];
            float4 vu = *(const float4*)&w1e[(size_t)(FF_ + n0 + row) * D_ + kt + c4];
            uint2 wg; wg.x = pk2(vg.x, vg.y); wg.y = pk2(vg.z, vg.w);
            uint2 wu; wu.x = pk2(vu.x, vu.y); wu.y = pk2(vu.z, vu.w);
            *(uint2*)&Bg[row][c4] = wg;
            *(uint2*)&Bu[row][c4] = wu;
        }
        __syncthreads();
        bf16x8 a[2], bg[4], bu[4];
        #pragma unroll
        for (int i = 0; i < 2; i++) a[i] = *(const bf16x8*)&As[wm + i * 16 + ml][quad * 8];
        #pragma unroll
        for (int j = 0; j < 4; j++) {
            bg[j] = *(const bf16x8*)&Bg[j * 16 + ml][quad * 8];
            bu[j] = *(const bf16x8*)&Bu[j * 16 + ml][quad * 8];
        }
        #pragma unroll
        for (int i = 0; i < 2; i++)
            #pragma unroll
            for (int j = 0; j < 4; j++) {
                ag[i][j] = __builtin_amdgcn_mfma_f32_16x16x32_bf16(a[i], bg[j], ag[i][j], 0, 0, 0);
                au[i][j] = __builtin_amdgcn_mfma_f32_16x16x32_bf16(a[i], bu[j], au[i][j], 0, 0, 0);
            }
        __syncthreads();
    }
    #pragma unroll
    for (int i = 0; i < 2; i++)
        #pragma unroll
        for (int j = 0; j < 4; j++)
            #pragma unroll
            for (int r = 0; r < 4; r++) {
                int m = m0 + wm + i * 16 + quad * 4 + r;
                if (m < nt) {
                    float g = ag[i][j][r], u = au[i][j][r];
                    float a = g / (1.f + __expf(-g)) * u;      // silu(g)*u
                    act[(size_t)(base + m) * FF_ + n0 + j * 16 + ml] = __float2bfloat16(a);
                }
            }
}

// ---------------- MoE w2 (MFMA): out0[tok] += wgt * (act @ w2e^T) ----------------
__global__ __launch_bounds__(256) void k_moe_w2(const bf16* __restrict__ act,
                                                const float* __restrict__ w2,
                                                const int* __restrict__ cnt,
                                                const int* __restrict__ off,
                                                const int* __restrict__ tok_list,
                                                const float* __restrict__ tok_w,
                                                float* __restrict__ out0) {
    int e = blockIdx.y >> 4, mt = blockIdx.y & 15;
    int m0 = mt * 128;
    int nt = min(cnt[e], T_);
    if (m0 >= nt) return;
    int n0 = blockIdx.x * 128;
    int base = off[e];
    __shared__ bf16 As[128][40];
    __shared__ bf16 Bs[128][40];
    int tid = threadIdx.x;
    int wave = tid >> 6, lane = tid & 63, ml = lane & 15, quad = lane >> 4;
    int wm = (wave >> 1) * 64, wn = (wave & 1) * 64;
    const float* w2e = w2 + (size_t)e * D_ * FF_;
    f32x4 acc[4][4] = {};
    for (int kt = 0; kt < FF_; kt += 32) {
        #pragma unroll
        for (int p = 0; p < 2; p++) {
            int ch = p * 256 + tid, row = ch >> 2, c8 = (ch & 3) << 3;
            uint4 v = make_uint4(0, 0, 0, 0);
            if (m0 + row < nt) v = *(const uint4*)&act[(size_t)(base + m0 + row) * FF_ + kt + c8];
            *(uint4*)&As[row][c8] = v;
        }
        #pragma unroll
        for (int p = 0; p < 4; p++) {
            int ch = p * 256 + tid, row = ch >> 3, c4 = (ch & 7) << 2;
            float4 v = *(const float4*)&w2e[(size_t)(n0 + row) * FF_ + kt + c4];
            uint2 w; w.x = pk2(v.x, v.y); w.y = pk2(v.z, v.w);
            *(uint2*)&Bs[row][c4] = w;
        }
        __syncthreads();
        bf16x8 a[4], b[4];
        #pragma unroll
        for (int i = 0; i < 4; i++) a[i] = *(const bf16x8*)&As[wm + i * 16 + ml][quad * 8];
        #pragma unroll
        for (int j = 0; j < 4; j++) b[j] = *(const bf16x8*)&Bs[wn + j * 16 + ml][quad * 8];
        #pragma unroll
        for (int i = 0; i < 4; i++)
            #pragma unroll
            for (int j = 0; j < 4; j++)
                acc[i][j] = __builtin_amdgcn_mfma_f32_16x16x32_bf16(a[i], b[j], acc[i][j], 0, 0, 0);
        __syncthreads();
    }
    #pragma unroll
    for (int i = 0; i < 4; i++)
        #pragma unroll
        for (int r = 0; r < 4; r++) {
            int m = m0 + wm + i * 16 + quad * 4 + r;
            if (m < nt) {
                int   tok = tok_list[e * T_ + m] & (T_ - 1);
                float wgt = tok_w[e * T_ + m];
                #pragma unroll
                for (int j = 0; j < 4; j++) {
                    int col = n0 + wn + j * 16 + ml;
                    atomicAdd(&out0[(size_t)tok * D_ + col], wgt * acc[i][j][r]);
                }
            }
        }
}

extern "C" void kernel_launch(void* const* d_in, const int* in_sizes, int n_in,
                              void* d_out, int out_size, void* d_ws, size_t ws_size,
                              hipStream_t stream) {
    const float* hidden     = (const float*)d_in[0];
    const float* residual   = (const float*)d_in[1];
    const float* op_norm_w  = (const float*)d_in[2];
    const float* ffn_norm_w = (const float*)d_in[3];
    const float* in_proj_w  = (const float*)d_in[4];
    const float* conv_w     = (const float*)d_in[5];
    const float* out_proj_w = (const float*)d_in[6];
    const float* gate_w     = (const float*)d_in[7];
    const float* gate_bias  = (const float*)d_in[8];
    const float* w1         = (const float*)d_in[9];
    const float* w2         = (const float*)d_in[10];

    // ---- workspace: ~32.3 MB ----
    char* p = (char*)d_ws;
    int*   cnt      = (int*)p;          p += 256;
    int*   off      = (int*)p;          p += 128;
    int*   tok_list = (int*)p;          p += (size_t)E_ * T_ * 4;       // 128 KB
    float* tok_w    = (float*)p;        p += (size_t)E_ * T_ * 4;       // 128 KB
    char*  regA     = p;                p += (size_t)T_ * D_ * 2 * 2;   // 8 MB
    char*  regB     = p;                p += (size_t)T_ * 3 * D_ * 4;   // 24 MB

    // regA: h1hi/h1lo -> cchi/cclo -> act (compact 8192 x FF bf16)
    bf16* h1hi = (bf16*)regA;
    bf16* h1lo = (bf16*)(regA + (size_t)T_ * D_ * 2);
    bf16* cchi = h1hi;
    bf16* cclo = h1lo;
    bf16* act  = (bf16*)regA;
    // regB: bcx (f32, 24 MB) -> y f32 [0:8) + h2 f32 [8:16) + h2b bf16 [16:20)
    float* bcx = (float*)regB;
    float* y   = (float*)regB;
    float* h2  = (float*)(regB + (size_t)T_ * D_ * 4);
    bf16*  h2b = (bf16*)(regB + (size_t)T_ * D_ * 8);

    float* out0 = (float*)d_out;                    // MoE output [T,D], f32 atomically accumulated
    float* res  = out0 + (size_t)T_ * D_;           // residual slot: res1 early, final residual later

    k_zero<<<(T_ * D_ + 255) / 256, 256, 0, stream>>>(out0, cnt);
    k_addnorm1<<<T_, 256, 0, stream>>>(hidden, residual, op_norm_w, h1hi, h1lo, res);
    k_gemm_split<<<dim3(3 * D_ / 128, T_ / 128), 256, 0, stream>>>(
        h1hi, h1lo, in_proj_w, bcx, T_, 3 * D_, D_);
    k_conv<<<T_, 256, 0, stream>>>(bcx, conv_w, cchi, cclo);
    k_gemm_split<<<dim3(D_ / 128, T_ / 128), 256, 0, stream>>>(
        cchi, cclo, out_proj_w, y, T_, D_, D_);
    k_addnorm2<<<T_, 256, 0, stream>>>(y, res, ffn_norm_w, h2, h2b);
    k_gate<<<T_, 256, 0, stream>>>(h2, gate_w, gate_bias, cnt, tok_list, tok_w);
    k_scan<<<1, 64, 0, stream>>>(cnt, off);
    k_moe_w1<<<dim3(FF_ / 64, E_ * (T_ / 128)), 256, 0, stream>>>(
        h2b, w1, cnt, off, tok_list, act);
    k_moe_w2<<<dim3(D_ / 128, E_ * (T_ / 128)), 256, 0, stream>>>(
        act, w2, cnt, off, tok_list, tok_w, out0);
}

// Round 7
// 475.068 us; speedup vs baseline: 4.9781x; 1.1661x over previous
//
#include <hip/hip_runtime.h>
#include <hip/hip_bf16.h>

// Problem constants (fixed by the reference)
#define T_  2048
#define D_  1024
#define FF_ 512
#define E_  16
#define K_  4
#define L_  3
static constexpr float EPS = 1e-5f;

typedef __hip_bfloat16 bf16;
typedef __attribute__((ext_vector_type(8))) short bf16x8;   // MFMA A/B frag (4 VGPRs)
typedef __attribute__((ext_vector_type(4))) float f32x4;    // MFMA C/D frag

__device__ __forceinline__ float b2f(bf16 x) { return __bfloat162float(x); }

__device__ __forceinline__ unsigned int pk2(float a, float b) {
    __hip_bfloat162 h = __float22bfloat162_rn(make_float2(a, b));
    unsigned int u; __builtin_memcpy(&u, &h, 4); return u;
}

// split f32x4 into bf16 hi + bf16 lo packed pairs (hi+lo ~ f32 precision)
__device__ __forceinline__ void split_pack(float4 v, uint2 &hi, uint2 &lo) {
    __hip_bfloat162 h01 = __float22bfloat162_rn(make_float2(v.x, v.y));
    __hip_bfloat162 h23 = __float22bfloat162_rn(make_float2(v.z, v.w));
    float2 r01 = make_float2(v.x - __bfloat162float(h01.x), v.y - __bfloat162float(h01.y));
    float2 r23 = make_float2(v.z - __bfloat162float(h23.x), v.w - __bfloat162float(h23.y));
    __hip_bfloat162 l01 = __float22bfloat162_rn(r01);
    __hip_bfloat162 l23 = __float22bfloat162_rn(r23);
    __builtin_memcpy(&hi.x, &h01, 4); __builtin_memcpy(&hi.y, &h23, 4);
    __builtin_memcpy(&lo.x, &l01, 4); __builtin_memcpy(&lo.y, &l23, 4);
}

// ---------------- zero out0 accumulator ----------------
__global__ __launch_bounds__(256) void k_zero(float* __restrict__ out0) {
    size_t i = (size_t)blockIdx.x * 256 + threadIdx.x;
    if (i < (size_t)T_ * D_) out0[i] = 0.f;
}

// ---------------- block reduction ----------------
__device__ __forceinline__ float blockReduceSum(float v) {
    #pragma unroll
    for (int off = 32; off > 0; off >>= 1) v += __shfl_down(v, off, 64);
    __shared__ float s[4];
    __shared__ float tot;
    int lane = threadIdx.x & 63, wid = threadIdx.x >> 6;
    if (lane == 0) s[wid] = v;
    __syncthreads();
    if (threadIdx.x == 0) tot = s[0] + s[1] + s[2] + s[3];
    __syncthreads();
    return tot;
}

// ---------------- addnorm1: h1 (hi/lo bf16) = rmsnorm(x+r)*w; res1(f32) = x+r ----------------
__global__ __launch_bounds__(256) void k_addnorm1(const float* __restrict__ x,
                                                  const float* __restrict__ r,
                                                  const float* __restrict__ w,
                                                  bf16* __restrict__ hhi,
                                                  bf16* __restrict__ hlo,
                                                  float* __restrict__ res) {
    int t = blockIdx.x, tid = threadIdx.x;
    float v[4]; float ss = 0.f;
    #pragma unroll
    for (int i = 0; i < 4; i++) {
        int d = tid + 256 * i;
        float s = x[(size_t)t * D_ + d] + r[(size_t)t * D_ + d];
        v[i] = s; ss += s * s;
    }
    float tot = blockReduceSum(ss);
    float rs = rsqrtf(tot / (float)D_ + EPS);
    #pragma unroll
    for (int i = 0; i < 4; i++) {
        int d = tid + 256 * i;
        res[(size_t)t * D_ + d] = v[i];
        float val = v[i] * rs * w[d];
        bf16 hi = __float2bfloat16(val);
        hhi[(size_t)t * D_ + d] = hi;
        hlo[(size_t)t * D_ + d] = __float2bfloat16(val - b2f(hi));
    }
}

// ---------------- addnorm2: h2(f32)+h2b(bf16) = rmsnorm(y+res)*w; res (in-place f32) = y+res ----
__global__ __launch_bounds__(256) void k_addnorm2(const float* __restrict__ y,
                                                  float* __restrict__ res,    // in-place update
                                                  const float* __restrict__ w,
                                                  float* __restrict__ h2,
                                                  bf16* __restrict__ h2b) {
    int t = blockIdx.x, tid = threadIdx.x;
    float v[4]; float ss = 0.f;
    #pragma unroll
    for (int i = 0; i < 4; i++) {
        int d = tid + 256 * i;
        float s = y[(size_t)t * D_ + d] + res[(size_t)t * D_ + d];
        v[i] = s; ss += s * s;
    }
    float tot = blockReduceSum(ss);
    float rs = rsqrtf(tot / (float)D_ + EPS);
    #pragma unroll
    for (int i = 0; i < 4; i++) {
        int d = tid + 256 * i;
        res[(size_t)t * D_ + d] = v[i];
        float val = v[i] * rs * w[d];
        h2[(size_t)t * D_ + d]  = val;
        h2b[(size_t)t * D_ + d] = __float2bfloat16(val);
    }
}

// ---------------- split-precision MFMA GEMM: C(f32)[M,N] = (Ah+Al)[M,K] @ (B f32)[N,K]^T ------
__global__ __launch_bounds__(256) void k_gemm_split(const bf16* __restrict__ Ah,
                                                    const bf16* __restrict__ Al,
                                                    const float* __restrict__ B,
                                                    float* __restrict__ C,
                                                    int M, int N, int K) {
    __shared__ bf16 Ash[128][40];
    __shared__ bf16 Asl[128][40];
    __shared__ bf16 Bsh[128][40];
    __shared__ bf16 Bsl[128][40];
    int m0 = blockIdx.y * 128, n0 = blockIdx.x * 128;
    int tid = threadIdx.x;
    int wave = tid >> 6, lane = tid & 63, ml = lane & 15, quad = lane >> 4;
    int wm = (wave >> 1) * 64, wn = (wave & 1) * 64;
    f32x4 acc[4][4] = {};
    for (int kt = 0; kt < K; kt += 32) {
        #pragma unroll
        for (int p = 0; p < 2; p++) {
            int ch = p * 256 + tid, row = ch >> 2, c8 = (ch & 3) << 3;
            *(uint4*)&Ash[row][c8] = *(const uint4*)&Ah[(size_t)(m0 + row) * K + kt + c8];
            *(uint4*)&Asl[row][c8] = *(const uint4*)&Al[(size_t)(m0 + row) * K + kt + c8];
        }
        #pragma unroll
        for (int p = 0; p < 4; p++) {
            int ch = p * 256 + tid, row = ch >> 3, c4 = (ch & 7) << 2;
            float4 v = *(const float4*)&B[(size_t)(n0 + row) * K + kt + c4];
            uint2 hi, lo; split_pack(v, hi, lo);
            *(uint2*)&Bsh[row][c4] = hi;
            *(uint2*)&Bsl[row][c4] = lo;
        }
        __syncthreads();
        bf16x8 ah[4], al[4], bh[4], bl[4];
        #pragma unroll
        for (int i = 0; i < 4; i++) {
            ah[i] = *(const bf16x8*)&Ash[wm + i * 16 + ml][quad * 8];
            al[i] = *(const bf16x8*)&Asl[wm + i * 16 + ml][quad * 8];
        }
        #pragma unroll
        for (int j = 0; j < 4; j++) {
            bh[j] = *(const bf16x8*)&Bsh[wn + j * 16 + ml][quad * 8];
            bl[j] = *(const bf16x8*)&Bsl[wn + j * 16 + ml][quad * 8];
        }
        #pragma unroll
        for (int i = 0; i < 4; i++)
            #pragma unroll
            for (int j = 0; j < 4; j++) {
                acc[i][j] = __builtin_amdgcn_mfma_f32_16x16x32_bf16(ah[i], bh[j], acc[i][j], 0, 0, 0);
                acc[i][j] = __builtin_amdgcn_mfma_f32_16x16x32_bf16(al[i], bh[j], acc[i][j], 0, 0, 0);
                acc[i][j] = __builtin_amdgcn_mfma_f32_16x16x32_bf16(ah[i], bl[j], acc[i][j], 0, 0, 0);
            }
        __syncthreads();
    }
    #pragma unroll
    for (int i = 0; i < 4; i++)
        #pragma unroll
        for (int j = 0; j < 4; j++)
            #pragma unroll
            for (int r = 0; r < 4; r++) {
                int row = m0 + wm + i * 16 + quad * 4 + r;   // C/D: row = quad*4+reg
                int col = n0 + wn + j * 16 + ml;             //      col = lane&15
                C[(size_t)row * N + col] = acc[i][j][r];
            }
}

// ---------------- conv (f32 in, hi/lo bf16 out): cc = C * sum_l Bx[t+l-2]*cw[:,l] ----------------
__global__ __launch_bounds__(256) void k_conv(const float* __restrict__ bcx,
                                              const float* __restrict__ cw,
                                              bf16* __restrict__ cchi,
                                              bf16* __restrict__ cclo) {
    int t = blockIdx.x, tid = threadIdx.x;
    #pragma unroll
    for (int i = 0; i < 4; i++) {
        int d = tid + 256 * i;
        float acc = 0.f;
        #pragma unroll
        for (int l = 0; l < L_; l++) {
            int tt = t + l - (L_ - 1);
            if (tt >= 0) {
                float bb = bcx[(size_t)tt * 3 * D_ + d];
                float xx = bcx[(size_t)tt * 3 * D_ + 2 * D_ + d];
                acc += bb * xx * cw[d * L_ + l];
            }
        }
        float c = bcx[(size_t)t * 3 * D_ + D_ + d];
        float val = c * acc;
        bf16 hi = __float2bfloat16(val);
        cchi[(size_t)t * D_ + d] = hi;
        cclo[(size_t)t * D_ + d] = __float2bfloat16(val - b2f(hi));
    }
}

// ---------------- gate (f32 h2): logits + top-4 -> dense choice arrays (NO atomics) ----------
__global__ __launch_bounds__(256) void k_gate(const float* __restrict__ h2,
                                              const float* __restrict__ gw,
                                              const float* __restrict__ gb,
                                              int4* __restrict__ choice_idx,
                                              float4* __restrict__ choice_wgt) {
    int t = blockIdx.x, tid = threadIdx.x;
    __shared__ float hs[D_];
    __shared__ float logits[E_];
    #pragma unroll
    for (int i = 0; i < 4; i++) { int d = tid + 256 * i; hs[d] = h2[(size_t)t * D_ + d]; }
    __syncthreads();
    int e = tid >> 4, j = tid & 15;
    float p = 0.f;
    for (int d = j; d < D_; d += 16) p += hs[d] * gw[(size_t)e * D_ + d];
    #pragma unroll
    for (int off = 8; off > 0; off >>= 1) p += __shfl_down(p, off, 64);
    if (j == 0) logits[e] = p;
    __syncthreads();
    if (tid == 0) {
        float sc[E_], ch[E_];
        #pragma unroll
        for (int i = 0; i < E_; i++) {
            float s = 1.f / (1.f + expf(-logits[i]));
            sc[i] = s; ch[i] = s + gb[i];
        }
        int idx[K_]; float wv[K_]; float wsum = 0.f;
        bool used[E_] = {};
        #pragma unroll
        for (int k = 0; k < K_; k++) {
            int best = 0; float bv = -1e30f;
            for (int i = 0; i < E_; i++)
                if (!used[i] && ch[i] > bv) { bv = ch[i]; best = i; }
            used[best] = true; idx[k] = best; wv[k] = sc[best]; wsum += sc[best];
        }
        float inv = 1.f / (wsum + 1e-20f);
        choice_idx[t] = make_int4(idx[0], idx[1], idx[2], idx[3]);
        choice_wgt[t] = make_float4(wv[0] * inv, wv[1] * inv, wv[2] * inv, wv[3] * inv);
    }
}

// ---------------- scatter: per-expert compaction of choices (ballot + LDS counter) ----------
__global__ __launch_bounds__(256) void k_scatter(const int4* __restrict__ choice_idx,
                                                 const float4* __restrict__ choice_wgt,
                                                 int* __restrict__ cnt,
                                                 int* __restrict__ tok_list,
                                                 float* __restrict__ tok_w) {
    int e = blockIdx.x;
    __shared__ int ctr;
    if (threadIdx.x == 0) ctr = 0;
    __syncthreads();
    int lane = threadIdx.x & 63;
    for (int t = threadIdx.x; t < T_; t += 256) {
        int4   ci = choice_idx[t];
        float4 cw = choice_wgt[t];
        bool m = false; float w = 0.f;
        if (ci.x == e) { m = true; w = cw.x; }
        else if (ci.y == e) { m = true; w = cw.y; }
        else if (ci.z == e) { m = true; w = cw.z; }
        else if (ci.w == e) { m = true; w = cw.w; }
        unsigned long long mask = __ballot(m);
        int loff = __popcll(mask & ((1ull << lane) - 1ull));
        int wcnt = __popcll(mask);
        int base = 0;
        if (lane == 0 && wcnt > 0) base = atomicAdd(&ctr, wcnt);   // LDS atomic: cheap
        base = __shfl(base, 0, 64);
        if (m) {
            tok_list[e * T_ + base + loff] = t;
            tok_w[e * T_ + base + loff]    = w;
        }
    }
    __syncthreads();
    if (threadIdx.x == 0) cnt[e] = ctr;
}

// ---------------- exclusive prefix sum over expert counts ----------------
__global__ void k_scan(const int* __restrict__ cnt, int* __restrict__ off) {
    if (threadIdx.x == 0) {
        int s = 0;
        for (int e = 0; e < E_; e++) { off[e] = s; s += min(cnt[e], T_); }
        off[E_] = s;
    }
}

// ---------------- MoE w1 (MFMA): act[base+m][n] = silu(g)*u over gathered token rows --------
__global__ __launch_bounds__(256) void k_moe_w1(const bf16* __restrict__ h2,
                                                const float* __restrict__ w1,
                                                const int* __restrict__ cnt,
                                                const int* __restrict__ off,
                                                const int* __restrict__ tok_list,
                                                bf16* __restrict__ act) {
    int e = blockIdx.y >> 4, mt = blockIdx.y & 15;
    int m0 = mt * 128;
    int nt = min(cnt[e], T_);
    if (m0 >= nt) return;
    int n0 = blockIdx.x * 64;
    int base = off[e];
    __shared__ bf16 As[128][40];
    __shared__ bf16 Bg[64][40];
    __shared__ bf16 Bu[64][40];
    __shared__ int  toks[128];
    int tid = threadIdx.x;
    if (tid < 128) {
        int m = m0 + tid;
        toks[tid] = ((m < nt) ? tok_list[e * T_ + m] : tok_list[e * T_]) & (T_ - 1);
    }
    __syncthreads();
    const float* w1e = w1 + (size_t)e * 2 * FF_ * D_;
    int wave = tid >> 6, lane = tid & 63, ml = lane & 15, quad = lane >> 4;
    int wm = wave * 32;
    f32x4 ag[2][4] = {}, au[2][4] = {};
    for (int kt = 0; kt < D_; kt += 32) {
        #pragma unroll
        for (int p = 0; p < 2; p++) {
            int ch = p * 256 + tid, row = ch >> 2, c8 = (ch & 3) << 3;
            *(uint4*)&As[row][c8] = *(const uint4*)&h2[(size_t)toks[row] * D_ + kt + c8];
        }
        #pragma unroll
        for (int p = 0; p < 2; p++) {
            int ch = p * 256 + tid, row = ch >> 3, c4 = (ch & 7) << 2;
            float4 vg = *(const float4*)&w1e[(size_t)(n0 + row) * D_ + kt + c4];
            float4 vu = *(const float4*)&w1e[(size_t)(FF_ + n0 + row) * D_ + kt + c4];
            uint2 wg; wg.x = pk2(vg.x, vg.y); wg.y = pk2(vg.z, vg.w);
            uint2 wu; wu.x = pk2(vu.x, vu.y); wu.y = pk2(vu.z, vu.w);
            *(uint2*)&Bg[row][c4] = wg;
            *(uint2*)&Bu[row][c4] = wu;
        }
        __syncthreads();
        bf16x8 a[2], bg[4], bu[4];
        #pragma unroll
        for (int i = 0; i < 2; i++) a[i] = *(const bf16x8*)&As[wm + i * 16 + ml][quad * 8];
        #pragma unroll
        for (int j = 0; j < 4; j++) {
            bg[j] = *(const bf16x8*)&Bg[j * 16 + ml][quad * 8];
            bu[j] = *(const bf16x8*)&Bu[j * 16 + ml][quad * 8];
        }
        #pragma unroll
        for (int i = 0; i < 2; i++)
            #pragma unroll
            for (int j = 0; j < 4; j++) {
                ag[i][j] = __builtin_amdgcn_mfma_f32_16x16x32_bf16(a[i], bg[j], ag[i][j], 0, 0, 0);
                au[i][j] = __builtin_amdgcn_mfma_f32_16x16x32_bf16(a[i], bu[j], au[i][j], 0, 0, 0);
            }
        __syncthreads();
    }
    #pragma unroll
    for (int i = 0; i < 2; i++)
        #pragma unroll
        for (int j = 0; j < 4; j++)
            #pragma unroll
            for (int r = 0; r < 4; r++) {
                int m = m0 + wm + i * 16 + quad * 4 + r;
                if (m < nt) {
                    float g = ag[i][j][r], u = au[i][j][r];
                    float a = g / (1.f + __expf(-g)) * u;      // silu(g)*u
                    act[(size_t)(base + m) * FF_ + n0 + j * 16 + ml] = __float2bfloat16(a);
                }
            }
}

// ---------------- MoE w2 (MFMA): out0[tok] += wgt * (act @ w2e^T) ----------------
__global__ __launch_bounds__(256) void k_moe_w2(const bf16* __restrict__ act,
                                                const float* __restrict__ w2,
                                                const int* __restrict__ cnt,
                                                const int* __restrict__ off,
                                                const int* __restrict__ tok_list,
                                                const float* __restrict__ tok_w,
                                                float* __restrict__ out0) {
    int e = blockIdx.y >> 4, mt = blockIdx.y & 15;
    int m0 = mt * 128;
    int nt = min(cnt[e], T_);
    if (m0 >= nt) return;
    int n0 = blockIdx.x * 128;
    int base = off[e];
    __shared__ bf16 As[128][40];
    __shared__ bf16 Bs[128][40];
    int tid = threadIdx.x;
    int wave = tid >> 6, lane = tid & 63, ml = lane & 15, quad = lane >> 4;
    int wm = (wave >> 1) * 64, wn = (wave & 1) * 64;
    const float* w2e = w2 + (size_t)e * D_ * FF_;
    f32x4 acc[4][4] = {};
    for (int kt = 0; kt < FF_; kt += 32) {
        #pragma unroll
        for (int p = 0; p < 2; p++) {
            int ch = p * 256 + tid, row = ch >> 2, c8 = (ch & 3) << 3;
            uint4 v = make_uint4(0, 0, 0, 0);
            if (m0 + row < nt) v = *(const uint4*)&act[(size_t)(base + m0 + row) * FF_ + kt + c8];
            *(uint4*)&As[row][c8] = v;
        }
        #pragma unroll
        for (int p = 0; p < 4; p++) {
            int ch = p * 256 + tid, row = ch >> 3, c4 = (ch & 7) << 2;
            float4 v = *(const float4*)&w2e[(size_t)(n0 + row) * FF_ + kt + c4];
            uint2 w; w.x = pk2(v.x, v.y); w.y = pk2(v.z, v.w);
            *(uint2*)&Bs[row][c4] = w;
        }
        __syncthreads();
        bf16x8 a[4], b[4];
        #pragma unroll
        for (int i = 0; i < 4; i++) a[i] = *(const bf16x8*)&As[wm + i * 16 + ml][quad * 8];
        #pragma unroll
        for (int j = 0; j < 4; j++) b[j] = *(const bf16x8*)&Bs[wn + j * 16 + ml][quad * 8];
        #pragma unroll
        for (int i = 0; i < 4; i++)
            #pragma unroll
            for (int j = 0; j < 4; j++)
                acc[i][j] = __builtin_amdgcn_mfma_f32_16x16x32_bf16(a[i], b[j], acc[i][j], 0, 0, 0);
        __syncthreads();
    }
    #pragma unroll
    for (int i = 0; i < 4; i++)
        #pragma unroll
        for (int r = 0; r < 4; r++) {
            int m = m0 + wm + i * 16 + quad * 4 + r;
            if (m < nt) {
                int   tok = tok_list[e * T_ + m] & (T_ - 1);
                float wgt = tok_w[e * T_ + m];
                #pragma unroll
                for (int j = 0; j < 4; j++) {
                    int col = n0 + wn + j * 16 + ml;
                    atomicAdd(&out0[(size_t)tok * D_ + col], wgt * acc[i][j][r]);
                }
            }
        }
}

extern "C" void kernel_launch(void* const* d_in, const int* in_sizes, int n_in,
                              void* d_out, int out_size, void* d_ws, size_t ws_size,
                              hipStream_t stream) {
    const float* hidden     = (const float*)d_in[0];
    const float* residual   = (const float*)d_in[1];
    const float* op_norm_w  = (const float*)d_in[2];
    const float* ffn_norm_w = (const float*)d_in[3];
    const float* in_proj_w  = (const float*)d_in[4];
    const float* conv_w     = (const float*)d_in[5];
    const float* out_proj_w = (const float*)d_in[6];
    const float* gate_w     = (const float*)d_in[7];
    const float* gate_bias  = (const float*)d_in[8];
    const float* w1         = (const float*)d_in[9];
    const float* w2         = (const float*)d_in[10];

    // ---- workspace: ~32.4 MB ----
    char* p = (char*)d_ws;
    int*    cnt        = (int*)p;        p += 256;
    int*    off        = (int*)p;        p += 128;
    int*    tok_list   = (int*)p;        p += (size_t)E_ * T_ * 4;      // 128 KB
    float*  tok_w      = (float*)p;      p += (size_t)E_ * T_ * 4;      // 128 KB
    int4*   choice_idx = (int4*)p;       p += (size_t)T_ * 16;          // 32 KB
    float4* choice_wgt = (float4*)p;     p += (size_t)T_ * 16;          // 32 KB
    char*   regA       = p;              p += (size_t)T_ * D_ * 2 * 2;  // 8 MB
    char*   regB       = p;              p += (size_t)T_ * 3 * D_ * 4;  // 24 MB

    // regA: h1hi/h1lo -> cchi/cclo -> act (compact 8192 x FF bf16)
    bf16* h1hi = (bf16*)regA;
    bf16* h1lo = (bf16*)(regA + (size_t)T_ * D_ * 2);
    bf16* cchi = h1hi;
    bf16* cclo = h1lo;
    bf16* act  = (bf16*)regA;
    // regB: bcx (f32, 24 MB) -> y f32 [0:8) + h2 f32 [8:16) + h2b bf16 [16:20)
    float* bcx = (float*)regB;
    float* y   = (float*)regB;
    float* h2  = (float*)(regB + (size_t)T_ * D_ * 4);
    bf16*  h2b = (bf16*)(regB + (size_t)T_ * D_ * 8);

    float* out0 = (float*)d_out;                    // MoE output [T,D], f32 atomically accumulated
    float* res  = out0 + (size_t)T_ * D_;           // residual slot: res1 early, final residual later

    k_zero<<<(T_ * D_ + 255) / 256, 256, 0, stream>>>(out0);
    k_addnorm1<<<T_, 256, 0, stream>>>(hidden, residual, op_norm_w, h1hi, h1lo, res);
    k_gemm_split<<<dim3(3 * D_ / 128, T_ / 128), 256, 0, stream>>>(
        h1hi, h1lo, in_proj_w, bcx, T_, 3 * D_, D_);
    k_conv<<<T_, 256, 0, stream>>>(bcx, conv_w, cchi, cclo);
    k_gemm_split<<<dim3(D_ / 128, T_ / 128), 256, 0, stream>>>(
        cchi, cclo, out_proj_w, y, T_, D_, D_);
    k_addnorm2<<<T_, 256, 0, stream>>>(y, res, ffn_norm_w, h2, h2b);
    k_gate<<<T_, 256, 0, stream>>>(h2, gate_w, gate_bias, choice_idx, choice_wgt);
    k_scatter<<<E_, 256, 0, stream>>>(choice_idx, choice_wgt, cnt, tok_list, tok_w);
    k_scan<<<1, 64, 0, stream>>>(cnt, off);
    k_moe_w1<<<dim3(FF_ / 64, E_ * (T_ / 128)), 256, 0, stream>>>(
        h2b, w1, cnt, off, tok_list, act);
    k_moe_w2<<<dim3(D_ / 128, E_ * (T_ / 128)), 256, 0, stream>>>(
        act, w2, cnt, off, tok_list, tok_w, out0);
}

// Round 8
// 448.008 us; speedup vs baseline: 5.2788x; 1.0604x over previous
//
#include <hip/hip_runtime.h>
#include <hip/hip_bf16.h>

// Problem constants (fixed by the reference)
#define T_  2048
#define D_  1024
#define FF_ 512
#define E_  16
#define K_  4
#define L_  3
static constexpr float EPS = 1e-5f;

typedef __hip_bfloat16 bf16;
typedef __attribute__((ext_vector_type(8))) short bf16x8;   // MFMA A/B frag (4 VGPRs)
typedef __attribute__((ext_vector_type(4))) float f32x4;    // MFMA C/D frag

__device__ __forceinline__ float b2f(bf16 x) { return __bfloat162float(x); }

__device__ __forceinline__ unsigned int pk2(float a, float b) {
    __hip_bfloat162 h = __float22bfloat162_rn(make_float2(a, b));
    unsigned int u; __builtin_memcpy(&u, &h, 4); return u;
}

// split f32x4 into bf16 hi + bf16 lo packed pairs (hi+lo ~ f32 precision)
__device__ __forceinline__ void split_pack(float4 v, uint2 &hi, uint2 &lo) {
    __hip_bfloat162 h01 = __float22bfloat162_rn(make_float2(v.x, v.y));
    __hip_bfloat162 h23 = __float22bfloat162_rn(make_float2(v.z, v.w));
    float2 r01 = make_float2(v.x - __bfloat162float(h01.x), v.y - __bfloat162float(h01.y));
    float2 r23 = make_float2(v.z - __bfloat162float(h23.x), v.w - __bfloat162float(h23.y));
    __hip_bfloat162 l01 = __float22bfloat162_rn(r01);
    __hip_bfloat162 l23 = __float22bfloat162_rn(r23);
    __builtin_memcpy(&hi.x, &h01, 4); __builtin_memcpy(&hi.y, &h23, 4);
    __builtin_memcpy(&lo.x, &l01, 4); __builtin_memcpy(&lo.y, &l23, 4);
}

// ================= weight pre-conversion (one memory-bound pass) =================
// w1,w2 -> plain bf16; in_proj,out_proj -> bf16 hi+lo pairs.
__global__ __launch_bounds__(256) void k_convert(const float* __restrict__ w1,
                                                 const float* __restrict__ w2,
                                                 const float* __restrict__ ipw,
                                                 const float* __restrict__ opw,
                                                 bf16* __restrict__ w1b,
                                                 bf16* __restrict__ w2b,
                                                 bf16* __restrict__ iph,
                                                 bf16* __restrict__ ipl,
                                                 bf16* __restrict__ oph,
                                                 bf16* __restrict__ opl) {
    const size_t n1 = (size_t)E_ * 2 * FF_ * D_;   // 16M
    const size_t n2 = (size_t)E_ * D_ * FF_;       // 8M
    const size_t n3 = (size_t)3 * D_ * D_;         // 3M
    const size_t n4 = (size_t)D_ * D_;             // 1M
    size_t i = ((size_t)blockIdx.x * 256 + threadIdx.x) * 4;
    if (i < n1) {
        float4 v = *(const float4*)&w1[i];
        uint2 h; h.x = pk2(v.x, v.y); h.y = pk2(v.z, v.w);
        *(uint2*)&w1b[i] = h;
    } else if (i < n1 + n2) {
        size_t j = i - n1;
        float4 v = *(const float4*)&w2[j];
        uint2 h; h.x = pk2(v.x, v.y); h.y = pk2(v.z, v.w);
        *(uint2*)&w2b[j] = h;
    } else if (i < n1 + n2 + n3) {
        size_t j = i - n1 - n2;
        float4 v = *(const float4*)&ipw[j];
        uint2 hi, lo; split_pack(v, hi, lo);
        *(uint2*)&iph[j] = hi;
        *(uint2*)&ipl[j] = lo;
    } else if (i < n1 + n2 + n3 + n4) {
        size_t j = i - n1 - n2 - n3;
        float4 v = *(const float4*)&opw[j];
        uint2 hi, lo; split_pack(v, hi, lo);
        *(uint2*)&oph[j] = hi;
        *(uint2*)&opl[j] = lo;
    }
}

// ---------------- zero out0 accumulator ----------------
__global__ __launch_bounds__(256) void k_zero(float* __restrict__ out0) {
    size_t i = (size_t)blockIdx.x * 256 + threadIdx.x;
    if (i < (size_t)T_ * D_) out0[i] = 0.f;
}

// ---------------- block reduction ----------------
__device__ __forceinline__ float blockReduceSum(float v) {
    #pragma unroll
    for (int off = 32; off > 0; off >>= 1) v += __shfl_down(v, off, 64);
    __shared__ float s[4];
    __shared__ float tot;
    int lane = threadIdx.x & 63, wid = threadIdx.x >> 6;
    if (lane == 0) s[wid] = v;
    __syncthreads();
    if (threadIdx.x == 0) tot = s[0] + s[1] + s[2] + s[3];
    __syncthreads();
    return tot;
}

// ---------------- addnorm1: h1 (hi/lo bf16) = rmsnorm(x+r)*w; res1(f32) = x+r ----------------
__global__ __launch_bounds__(256) void k_addnorm1(const float* __restrict__ x,
                                                  const float* __restrict__ r,
                                                  const float* __restrict__ w,
                                                  bf16* __restrict__ hhi,
                                                  bf16* __restrict__ hlo,
                                                  float* __restrict__ res) {
    int t = blockIdx.x, tid = threadIdx.x;
    float v[4]; float ss = 0.f;
    #pragma unroll
    for (int i = 0; i < 4; i++) {
        int d = tid + 256 * i;
        float s = x[(size_t)t * D_ + d] + r[(size_t)t * D_ + d];
        v[i] = s; ss += s * s;
    }
    float tot = blockReduceSum(ss);
    float rs = rsqrtf(tot / (float)D_ + EPS);
    #pragma unroll
    for (int i = 0; i < 4; i++) {
        int d = tid + 256 * i;
        res[(size_t)t * D_ + d] = v[i];
        float val = v[i] * rs * w[d];
        bf16 hi = __float2bfloat16(val);
        hhi[(size_t)t * D_ + d] = hi;
        hlo[(size_t)t * D_ + d] = __float2bfloat16(val - b2f(hi));
    }
}

// ---------------- addnorm2: h2(f32)+h2b(bf16) = rmsnorm(y+res)*w; res (in-place f32) ----------
__global__ __launch_bounds__(256) void k_addnorm2(const float* __restrict__ y,
                                                  float* __restrict__ res,
                                                  const float* __restrict__ w,
                                                  float* __restrict__ h2,
                                                  bf16* __restrict__ h2b) {
    int t = blockIdx.x, tid = threadIdx.x;
    float v[4]; float ss = 0.f;
    #pragma unroll
    for (int i = 0; i < 4; i++) {
        int d = tid + 256 * i;
        float s = y[(size_t)t * D_ + d] + res[(size_t)t * D_ + d];
        v[i] = s; ss += s * s;
    }
    float tot = blockReduceSum(ss);
    float rs = rsqrtf(tot / (float)D_ + EPS);
    #pragma unroll
    for (int i = 0; i < 4; i++) {
        int d = tid + 256 * i;
        res[(size_t)t * D_ + d] = v[i];
        float val = v[i] * rs * w[d];
        h2[(size_t)t * D_ + d]  = val;
        h2b[(size_t)t * D_ + d] = __float2bfloat16(val);
    }
}

// ======== split-precision MFMA GEMM, PRE-SPLIT B: C = (Ah+Al) @ (Bh+Bl)^T (3-term) ========
__global__ __launch_bounds__(256) void k_gemm_split2(const bf16* __restrict__ Ah,
                                                     const bf16* __restrict__ Al,
                                                     const bf16* __restrict__ Bh,
                                                     const bf16* __restrict__ Bl,
                                                     float* __restrict__ C,
                                                     int M, int N, int K) {
    __shared__ bf16 Ash[128][40];
    __shared__ bf16 Asl[128][40];
    __shared__ bf16 Bsh[128][40];
    __shared__ bf16 Bsl[128][40];
    int m0 = blockIdx.y * 128, n0 = blockIdx.x * 128;
    int tid = threadIdx.x;
    int wave = tid >> 6, lane = tid & 63, ml = lane & 15, quad = lane >> 4;
    int wm = (wave >> 1) * 64, wn = (wave & 1) * 64;
    f32x4 acc[4][4] = {};
    for (int kt = 0; kt < K; kt += 32) {
        #pragma unroll
        for (int p = 0; p < 2; p++) {
            int ch = p * 256 + tid, row = ch >> 2, c8 = (ch & 3) << 3;
            *(uint4*)&Ash[row][c8] = *(const uint4*)&Ah[(size_t)(m0 + row) * K + kt + c8];
            *(uint4*)&Asl[row][c8] = *(const uint4*)&Al[(size_t)(m0 + row) * K + kt + c8];
            *(uint4*)&Bsh[row][c8] = *(const uint4*)&Bh[(size_t)(n0 + row) * K + kt + c8];
            *(uint4*)&Bsl[row][c8] = *(const uint4*)&Bl[(size_t)(n0 + row) * K + kt + c8];
        }
        __syncthreads();
        bf16x8 ah[4], al[4], bh[4], bl[4];
        #pragma unroll
        for (int i = 0; i < 4; i++) {
            ah[i] = *(const bf16x8*)&Ash[wm + i * 16 + ml][quad * 8];
            al[i] = *(const bf16x8*)&Asl[wm + i * 16 + ml][quad * 8];
        }
        #pragma unroll
        for (int j = 0; j < 4; j++) {
            bh[j] = *(const bf16x8*)&Bsh[wn + j * 16 + ml][quad * 8];
            bl[j] = *(const bf16x8*)&Bsl[wn + j * 16 + ml][quad * 8];
        }
        #pragma unroll
        for (int i = 0; i < 4; i++)
            #pragma unroll
            for (int j = 0; j < 4; j++) {
                acc[i][j] = __builtin_amdgcn_mfma_f32_16x16x32_bf16(ah[i], bh[j], acc[i][j], 0, 0, 0);
                acc[i][j] = __builtin_amdgcn_mfma_f32_16x16x32_bf16(al[i], bh[j], acc[i][j], 0, 0, 0);
                acc[i][j] = __builtin_amdgcn_mfma_f32_16x16x32_bf16(ah[i], bl[j], acc[i][j], 0, 0, 0);
            }
        __syncthreads();
    }
    #pragma unroll
    for (int i = 0; i < 4; i++)
        #pragma unroll
        for (int j = 0; j < 4; j++)
            #pragma unroll
            for (int r = 0; r < 4; r++) {
                int row = m0 + wm + i * 16 + quad * 4 + r;   // C/D: row = quad*4+reg
                int col = n0 + wn + j * 16 + ml;             //      col = lane&15
                C[(size_t)row * N + col] = acc[i][j][r];
            }
}

// ---- fallback (f32 B, in-block split) — round-7 verified ----
__global__ __launch_bounds__(256) void k_gemm_split(const bf16* __restrict__ Ah,
                                                    const bf16* __restrict__ Al,
                                                    const float* __restrict__ B,
                                                    float* __restrict__ C,
                                                    int M, int N, int K) {
    __shared__ bf16 Ash[128][40];
    __shared__ bf16 Asl[128][40];
    __shared__ bf16 Bsh[128][40];
    __shared__ bf16 Bsl[128][40];
    int m0 = blockIdx.y * 128, n0 = blockIdx.x * 128;
    int tid = threadIdx.x;
    int wave = tid >> 6, lane = tid & 63, ml = lane & 15, quad = lane >> 4;
    int wm = (wave >> 1) * 64, wn = (wave & 1) * 64;
    f32x4 acc[4][4] = {};
    for (int kt = 0; kt < K; kt += 32) {
        #pragma unroll
        for (int p = 0; p < 2; p++) {
            int ch = p * 256 + tid, row = ch >> 2, c8 = (ch & 3) << 3;
            *(uint4*)&Ash[row][c8] = *(const uint4*)&Ah[(size_t)(m0 + row) * K + kt + c8];
            *(uint4*)&Asl[row][c8] = *(const uint4*)&Al[(size_t)(m0 + row) * K + kt + c8];
        }
        #pragma unroll
        for (int p = 0; p < 4; p++) {
            int ch = p * 256 + tid, row = ch >> 3, c4 = (ch & 7) << 2;
            float4 v = *(const float4*)&B[(size_t)(n0 + row) * K + kt + c4];
            uint2 hi, lo; split_pack(v, hi, lo);
            *(uint2*)&Bsh[row][c4] = hi;
            *(uint2*)&Bsl[row][c4] = lo;
        }
        __syncthreads();
        bf16x8 ah[4], al[4], bh[4], bl[4];
        #pragma unroll
        for (int i = 0; i < 4; i++) {
            ah[i] = *(const bf16x8*)&Ash[wm + i * 16 + ml][quad * 8];
            al[i] = *(const bf16x8*)&Asl[wm + i * 16 + ml][quad * 8];
        }
        #pragma unroll
        for (int j = 0; j < 4; j++) {
            bh[j] = *(const bf16x8*)&Bsh[wn + j * 16 + ml][quad * 8];
            bl[j] = *(const bf16x8*)&Bsl[wn + j * 16 + ml][quad * 8];
        }
        #pragma unroll
        for (int i = 0; i < 4; i++)
            #pragma unroll
            for (int j = 0; j < 4; j++) {
                acc[i][j] = __builtin_amdgcn_mfma_f32_16x16x32_bf16(ah[i], bh[j], acc[i][j], 0, 0, 0);
                acc[i][j] = __builtin_amdgcn_mfma_f32_16x16x32_bf16(al[i], bh[j], acc[i][j], 0, 0, 0);
                acc[i][j] = __builtin_amdgcn_mfma_f32_16x16x32_bf16(ah[i], bl[j], acc[i][j], 0, 0, 0);
            }
        __syncthreads();
    }
    #pragma unroll
    for (int i = 0; i < 4; i++)
        #pragma unroll
        for (int j = 0; j < 4; j++)
            #pragma unroll
            for (int r = 0; r < 4; r++) {
                int row = m0 + wm + i * 16 + quad * 4 + r;
                int col = n0 + wn + j * 16 + ml;
                C[(size_t)row * N + col] = acc[i][j][r];
            }
}

// ---------------- conv (f32 in, hi/lo bf16 out) ----------------
__global__ __launch_bounds__(256) void k_conv(const float* __restrict__ bcx,
                                              const float* __restrict__ cw,
                                              bf16* __restrict__ cchi,
                                              bf16* __restrict__ cclo) {
    int t = blockIdx.x, tid = threadIdx.x;
    #pragma unroll
    for (int i = 0; i < 4; i++) {
        int d = tid + 256 * i;
        float acc = 0.f;
        #pragma unroll
        for (int l = 0; l < L_; l++) {
            int tt = t + l - (L_ - 1);
            if (tt >= 0) {
                float bb = bcx[(size_t)tt * 3 * D_ + d];
                float xx = bcx[(size_t)tt * 3 * D_ + 2 * D_ + d];
                acc += bb * xx * cw[d * L_ + l];
            }
        }
        float c = bcx[(size_t)t * 3 * D_ + D_ + d];
        float val = c * acc;
        bf16 hi = __float2bfloat16(val);
        cchi[(size_t)t * D_ + d] = hi;
        cclo[(size_t)t * D_ + d] = __float2bfloat16(val - b2f(hi));
    }
}

// ---------------- gate (f32 h2): logits + top-4 -> dense choice arrays (NO atomics) ----------
__global__ __launch_bounds__(256) void k_gate(const float* __restrict__ h2,
                                              const float* __restrict__ gw,
                                              const float* __restrict__ gb,
                                              int4* __restrict__ choice_idx,
                                              float4* __restrict__ choice_wgt) {
    int t = blockIdx.x, tid = threadIdx.x;
    __shared__ float hs[D_];
    __shared__ float logits[E_];
    #pragma unroll
    for (int i = 0; i < 4; i++) { int d = tid + 256 * i; hs[d] = h2[(size_t)t * D_ + d]; }
    __syncthreads();
    int e = tid >> 4, j = tid & 15;
    float p = 0.f;
    for (int d = j; d < D_; d += 16) p += hs[d] * gw[(size_t)e * D_ + d];
    #pragma unroll
    for (int off = 8; off > 0; off >>= 1) p += __shfl_down(p, off, 64);
    if (j == 0) logits[e] = p;
    __syncthreads();
    if (tid == 0) {
        float sc[E_], ch[E_];
        #pragma unroll
        for (int i = 0; i < E_; i++) {
            float s = 1.f / (1.f + expf(-logits[i]));
            sc[i] = s; ch[i] = s + gb[i];
        }
        int idx[K_]; float wv[K_]; float wsum = 0.f;
        bool used[E_] = {};
        #pragma unroll
        for (int k = 0; k < K_; k++) {
            int best = 0; float bv = -1e30f;
            for (int i = 0; i < E_; i++)
                if (!used[i] && ch[i] > bv) { bv = ch[i]; best = i; }
            used[best] = true; idx[k] = best; wv[k] = sc[best]; wsum += sc[best];
        }
        float inv = 1.f / (wsum + 1e-20f);
        choice_idx[t] = make_int4(idx[0], idx[1], idx[2], idx[3]);
        choice_wgt[t] = make_float4(wv[0] * inv, wv[1] * inv, wv[2] * inv, wv[3] * inv);
    }
}

// ---------------- scatter: per-expert compaction (ballot + LDS counter) ----------
__global__ __launch_bounds__(256) void k_scatter(const int4* __restrict__ choice_idx,
                                                 const float4* __restrict__ choice_wgt,
                                                 int* __restrict__ cnt,
                                                 int* __restrict__ tok_list,
                                                 float* __restrict__ tok_w) {
    int e = blockIdx.x;
    __shared__ int ctr;
    if (threadIdx.x == 0) ctr = 0;
    __syncthreads();
    int lane = threadIdx.x & 63;
    for (int t = threadIdx.x; t < T_; t += 256) {
        int4   ci = choice_idx[t];
        float4 cw = choice_wgt[t];
        bool m = false; float w = 0.f;
        if (ci.x == e) { m = true; w = cw.x; }
        else if (ci.y == e) { m = true; w = cw.y; }
        else if (ci.z == e) { m = true; w = cw.z; }
        else if (ci.w == e) { m = true; w = cw.w; }
        unsigned long long mask = __ballot(m);
        int loff = __popcll(mask & ((1ull << lane) - 1ull));
        int wcnt = __popcll(mask);
        int base = 0;
        if (lane == 0 && wcnt > 0) base = atomicAdd(&ctr, wcnt);
        base = __shfl(base, 0, 64);
        if (m) {
            tok_list[e * T_ + base + loff] = t;
            tok_w[e * T_ + base + loff]    = w;
        }
    }
    __syncthreads();
    if (threadIdx.x == 0) cnt[e] = ctr;
}

// ---------------- exclusive prefix sum over expert counts ----------------
__global__ void k_scan(const int* __restrict__ cnt, int* __restrict__ off) {
    if (threadIdx.x == 0) {
        int s = 0;
        for (int e = 0; e < E_; e++) { off[e] = s; s += min(cnt[e], T_); }
        off[E_] = s;
    }
}

// ======== MoE w1 (MFMA), PRE-CONVERTED bf16 weights ========
__global__ __launch_bounds__(256) void k_moe_w1_pre(const bf16* __restrict__ h2,
                                                    const bf16* __restrict__ w1b,
                                                    const int* __restrict__ cnt,
                                                    const int* __restrict__ off,
                                                    const int* __restrict__ tok_list,
                                                    bf16* __restrict__ act) {
    int e = blockIdx.y >> 4, mt = blockIdx.y & 15;
    int m0 = mt * 128;
    int nt = min(cnt[e], T_);
    if (m0 >= nt) return;
    int n0 = blockIdx.x * 64;
    int base = off[e];
    __shared__ bf16 As[128][40];
    __shared__ bf16 Bg[64][40];
    __shared__ bf16 Bu[64][40];
    __shared__ int  toks[128];
    int tid = threadIdx.x;
    if (tid < 128) {
        int m = m0 + tid;
        toks[tid] = ((m < nt) ? tok_list[e * T_ + m] : tok_list[e * T_]) & (T_ - 1);
    }
    __syncthreads();
    const bf16* w1e = w1b + (size_t)e * 2 * FF_ * D_;
    int wave = tid >> 6, lane = tid & 63, ml = lane & 15, quad = lane >> 4;
    int wm = wave * 32;
    f32x4 ag[2][4] = {}, au[2][4] = {};
    for (int kt = 0; kt < D_; kt += 32) {
        #pragma unroll
        for (int p = 0; p < 2; p++) {
            int ch = p * 256 + tid, row = ch >> 2, c8 = (ch & 3) << 3;
            *(uint4*)&As[row][c8] = *(const uint4*)&h2[(size_t)toks[row] * D_ + kt + c8];
        }
        {
            int row = tid >> 2, c8 = (tid & 3) << 3;   // 64 rows x 4 chunks = 256
            *(uint4*)&Bg[row][c8] = *(const uint4*)&w1e[(size_t)(n0 + row) * D_ + kt + c8];
            *(uint4*)&Bu[row][c8] = *(const uint4*)&w1e[(size_t)(FF_ + n0 + row) * D_ + kt + c8];
        }
        __syncthreads();
        bf16x8 a[2], bg[4], bu[4];
        #pragma unroll
        for (int i = 0; i < 2; i++) a[i] = *(const bf16x8*)&As[wm + i * 16 + ml][quad * 8];
        #pragma unroll
        for (int j = 0; j < 4; j++) {
            bg[j] = *(const bf16x8*)&Bg[j * 16 + ml][quad * 8];
            bu[j] = *(const bf16x8*)&Bu[j * 16 + ml][quad * 8];
        }
        #pragma unroll
        for (int i = 0; i < 2; i++)
            #pragma unroll
            for (int j = 0; j < 4; j++) {
                ag[i][j] = __builtin_amdgcn_mfma_f32_16x16x32_bf16(a[i], bg[j], ag[i][j], 0, 0, 0);
                au[i][j] = __builtin_amdgcn_mfma_f32_16x16x32_bf16(a[i], bu[j], au[i][j], 0, 0, 0);
            }
        __syncthreads();
    }
    #pragma unroll
    for (int i = 0; i < 2; i++)
        #pragma unroll
        for (int j = 0; j < 4; j++)
            #pragma unroll
            for (int r = 0; r < 4; r++) {
                int m = m0 + wm + i * 16 + quad * 4 + r;
                if (m < nt) {
                    float g = ag[i][j][r], u = au[i][j][r];
                    float a = g / (1.f + __expf(-g)) * u;
                    act[(size_t)(base + m) * FF_ + n0 + j * 16 + ml] = __float2bfloat16(a);
                }
            }
}

// ---- fallback w1 (f32 weights) — round-7 verified ----
__global__ __launch_bounds__(256) void k_moe_w1(const bf16* __restrict__ h2,
                                                const float* __restrict__ w1,
                                                const int* __restrict__ cnt,
                                                const int* __restrict__ off,
                                                const int* __restrict__ tok_list,
                                                bf16* __restrict__ act) {
    int e = blockIdx.y >> 4, mt = blockIdx.y & 15;
    int m0 = mt * 128;
    int nt = min(cnt[e], T_);
    if (m0 >= nt) return;
    int n0 = blockIdx.x * 64;
    int base = off[e];
    __shared__ bf16 As[128][40];
    __shared__ bf16 Bg[64][40];
    __shared__ bf16 Bu[64][40];
    __shared__ int  toks[128];
    int tid = threadIdx.x;
    if (tid < 128) {
        int m = m0 + tid;
        toks[tid] = ((m < nt) ? tok_list[e * T_ + m] : tok_list[e * T_]) & (T_ - 1);
    }
    __syncthreads();
    const float* w1e = w1 + (size_t)e * 2 * FF_ * D_;
    int wave = tid >> 6, lane = tid & 63, ml = lane & 15, quad = lane >> 4;
    int wm = wave * 32;
    f32x4 ag[2][4] = {}, au[2][4] = {};
    for (int kt = 0; kt < D_; kt += 32) {
        #pragma unroll
        for (int p = 0; p < 2; p++) {
            int ch = p * 256 + tid, row = ch >> 2, c8 = (ch & 3) << 3;
            *(uint4*)&As[row][c8] = *(const uint4*)&h2[(size_t)toks[row] * D_ + kt + c8];
        }
        #pragma unroll
        for (int p = 0; p < 2; p++) {
            int ch = p * 256 + tid, row = ch >> 3, c4 = (ch & 7) << 2;
            float4 vg = *(const float4*)&w1e[(size_t)(n0 + row) * D_ + kt + c4];
            float4 vu = *(const float4*)&w1e[(size_t)(FF_ + n0 + row) * D_ + kt + c4];
            uint2 wg; wg.x = pk2(vg.x, vg.y); wg.y = pk2(vg.z, vg.w);
            uint2 wu; wu.x = pk2(vu.x, vu.y); wu.y = pk2(vu.z, vu.w);
            *(uint2*)&Bg[row][c4] = wg;
            *(uint2*)&Bu[row][c4] = wu;
        }
        __syncthreads();
        bf16x8 a[2], bg[4], bu[4];
        #pragma unroll
        for (int i = 0; i < 2; i++) a[i] = *(const bf16x8*)&As[wm + i * 16 + ml][quad * 8];
        #pragma unroll
        for (int j = 0; j < 4; j++) {
            bg[j] = *(const bf16x8*)&Bg[j * 16 + ml][quad * 8];
            bu[j] = *(const bf16x8*)&Bu[j * 16 + ml][quad * 8];
        }
        #pragma unroll
        for (int i = 0; i < 2; i++)
            #pragma unroll
            for (int j = 0; j < 4; j++) {
                ag[i][j] = __builtin_amdgcn_mfma_f32_16x16x32_bf16(a[i], bg[j], ag[i][j], 0, 0, 0);
                au[i][j] = __builtin_amdgcn_mfma_f32_16x16x32_bf16(a[i], bu[j], au[i][j], 0, 0, 0);
            }
        __syncthreads();
    }
    #pragma unroll
    for (int i = 0; i < 2; i++)
        #pragma unroll
        for (int j = 0; j < 4; j++)
            #pragma unroll
            for (int r = 0; r < 4; r++) {
                int m = m0 + wm + i * 16 + quad * 4 + r;
                if (m < nt) {
                    float g = ag[i][j][r], u = au[i][j][r];
                    float a = g / (1.f + __expf(-g)) * u;
                    act[(size_t)(base + m) * FF_ + n0 + j * 16 + ml] = __float2bfloat16(a);
                }
            }
}

// ======== MoE w2 (MFMA), PRE-CONVERTED bf16 weights ========
__global__ __launch_bounds__(256) void k_moe_w2_pre(const bf16* __restrict__ act,
                                                    const bf16* __restrict__ w2b,
                                                    const int* __restrict__ cnt,
                                                    const int* __restrict__ off,
                                                    const int* __restrict__ tok_list,
                                                    const float* __restrict__ tok_w,
                                                    float* __restrict__ out0) {
    int e = blockIdx.y >> 4, mt = blockIdx.y & 15;
    int m0 = mt * 128;
    int nt = min(cnt[e], T_);
    if (m0 >= nt) return;
    int n0 = blockIdx.x * 128;
    int base = off[e];
    __shared__ bf16 As[128][40];
    __shared__ bf16 Bs[128][40];
    int tid = threadIdx.x;
    int wave = tid >> 6, lane = tid & 63, ml = lane & 15, quad = lane >> 4;
    int wm = (wave >> 1) * 64, wn = (wave & 1) * 64;
    const bf16* w2e = w2b + (size_t)e * D_ * FF_;
    f32x4 acc[4][4] = {};
    for (int kt = 0; kt < FF_; kt += 32) {
        #pragma unroll
        for (int p = 0; p < 2; p++) {
            int ch = p * 256 + tid, row = ch >> 2, c8 = (ch & 3) << 3;
            uint4 v = make_uint4(0, 0, 0, 0);
            if (m0 + row < nt) v = *(const uint4*)&act[(size_t)(base + m0 + row) * FF_ + kt + c8];
            *(uint4*)&As[row][c8] = v;
            *(uint4*)&Bs[row][c8] = *(const uint4*)&w2e[(size_t)(n0 + row) * FF_ + kt + c8];
        }
        __syncthreads();
        bf16x8 a[4], b[4];
        #pragma unroll
        for (int i = 0; i < 4; i++) a[i] = *(const bf16x8*)&As[wm + i * 16 + ml][quad * 8];
        #pragma unroll
        for (int j = 0; j < 4; j++) b[j] = *(const bf16x8*)&Bs[wn + j * 16 + ml][quad * 8];
        #pragma unroll
        for (int i = 0; i < 4; i++)
            #pragma unroll
            for (int j = 0; j < 4; j++)
                acc[i][j] = __builtin_amdgcn_mfma_f32_16x16x32_bf16(a[i], b[j], acc[i][j], 0, 0, 0);
        __syncthreads();
    }
    #pragma unroll
    for (int i = 0; i < 4; i++)
        #pragma unroll
        for (int r = 0; r < 4; r++) {
            int m = m0 + wm + i * 16 + quad * 4 + r;
            if (m < nt) {
                int   tok = tok_list[e * T_ + m] & (T_ - 1);
                float wgt = tok_w[e * T_ + m];
                #pragma unroll
                for (int j = 0; j < 4; j++) {
                    int col = n0 + wn + j * 16 + ml;
                    atomicAdd(&out0[(size_t)tok * D_ + col], wgt * acc[i][j][r]);
                }
            }
        }
}

// ---- fallback w2 (f32 weights) — round-7 verified ----
__global__ __launch_bounds__(256) void k_moe_w2(const bf16* __restrict__ act,
                                                const float* __restrict__ w2,
                                                const int* __restrict__ cnt,
                                                const int* __restrict__ off,
                                                const int* __restrict__ tok_list,
                                                const float* __restrict__ tok_w,
                                                float* __restrict__ out0) {
    int e = blockIdx.y >> 4, mt = blockIdx.y & 15;
    int m0 = mt * 128;
    int nt = min(cnt[e], T_);
    if (m0 >= nt) return;
    int n0 = blockIdx.x * 128;
    int base = off[e];
    __shared__ bf16 As[128][40];
    __shared__ bf16 Bs[128][40];
    int tid = threadIdx.x;
    int wave = tid >> 6, lane = tid & 63, ml = lane & 15, quad = lane >> 4;
    int wm = (wave >> 1) * 64, wn = (wave & 1) * 64;
    const float* w2e = w2 + (size_t)e * D_ * FF_;
    f32x4 acc[4][4] = {};
    for (int kt = 0; kt < FF_; kt += 32) {
        #pragma unroll
        for (int p = 0; p < 2; p++) {
            int ch = p * 256 + tid, row = ch >> 2, c8 = (ch & 3) << 3;
            uint4 v = make_uint4(0, 0, 0, 0);
            if (m0 + row < nt) v = *(const uint4*)&act[(size_t)(base + m0 + row) * FF_ + kt + c8];
            *(uint4*)&As[row][c8] = v;
        }
        #pragma unroll
        for (int p = 0; p < 4; p++) {
            int ch = p * 256 + tid, row = ch >> 3, c4 = (ch & 7) << 2;
            float4 v = *(const float4*)&w2e[(size_t)(n0 + row) * FF_ + kt + c4];
            uint2 w; w.x = pk2(v.x, v.y); w.y = pk2(v.z, v.w);
            *(uint2*)&Bs[row][c4] = w;
        }
        __syncthreads();
        bf16x8 a[4], b[4];
        #pragma unroll
        for (int i = 0; i < 4; i++) a[i] = *(const bf16x8*)&As[wm + i * 16 + ml][quad * 8];
        #pragma unroll
        for (int j = 0; j < 4; j++) b[j] = *(const bf16x8*)&Bs[wn + j * 16 + ml][quad * 8];
        #pragma unroll
        for (int i = 0; i < 4; i++)
            #pragma unroll
            for (int j = 0; j < 4; j++)
                acc[i][j] = __builtin_amdgcn_mfma_f32_16x16x32_bf16(a[i], b[j], acc[i][j], 0, 0, 0);
        __syncthreads();
    }
    #pragma unroll
    for (int i = 0; i < 4; i++)
        #pragma unroll
        for (int r = 0; r < 4; r++) {
            int m = m0 + wm + i * 16 + quad * 4 + r;
            if (m < nt) {
                int   tok = tok_list[e * T_ + m] & (T_ - 1);
                float wgt = tok_w[e * T_ + m];
                #pragma unroll
                for (int j = 0; j < 4; j++) {
                    int col = n0 + wn + j * 16 + ml;
                    atomicAdd(&out0[(size_t)tok * D_ + col], wgt * acc[i][j][r]);
                }
            }
        }
}

extern "C" void kernel_launch(void* const* d_in, const int* in_sizes, int n_in,
                              void* d_out, int out_size, void* d_ws, size_t ws_size,
                              hipStream_t stream) {
    const float* hidden     = (const float*)d_in[0];
    const float* residual   = (const float*)d_in[1];
    const float* op_norm_w  = (const float*)d_in[2];
    const float* ffn_norm_w = (const float*)d_in[3];
    const float* in_proj_w  = (const float*)d_in[4];
    const float* conv_w     = (const float*)d_in[5];
    const float* out_proj_w = (const float*)d_in[6];
    const float* gate_w     = (const float*)d_in[7];
    const float* gate_bias  = (const float*)d_in[8];
    const float* w1         = (const float*)d_in[9];
    const float* w2         = (const float*)d_in[10];

    // ---- base workspace (~32.5 MB) ----
    char* p = (char*)d_ws;
    int*    cnt        = (int*)p;        p += 256;
    int*    off        = (int*)p;        p += 128;
    int*    tok_list   = (int*)p;        p += (size_t)E_ * T_ * 4;      // 128 KB
    float*  tok_w      = (float*)p;      p += (size_t)E_ * T_ * 4;      // 128 KB
    int4*   choice_idx = (int4*)p;       p += (size_t)T_ * 16;          // 32 KB
    float4* choice_wgt = (float4*)p;     p += (size_t)T_ * 16;          // 32 KB
    char*   regA       = p;              p += (size_t)T_ * D_ * 2 * 2;  // 8 MB
    char*   regB       = p;              p += (size_t)T_ * 3 * D_ * 4;  // 24 MB

    // pre-converted weight area (~64 MB, optional)
    const size_t n1 = (size_t)E_ * 2 * FF_ * D_;   // w1 elements
    const size_t n2 = (size_t)E_ * D_ * FF_;       // w2
    const size_t n3 = (size_t)3 * D_ * D_;         // in_proj
    const size_t n4 = (size_t)D_ * D_;             // out_proj
    bf16* w1b = (bf16*)p;  p += n1 * 2;
    bf16* w2b = (bf16*)p;  p += n2 * 2;
    bf16* iph = (bf16*)p;  p += n3 * 2;
    bf16* ipl = (bf16*)p;  p += n3 * 2;
    bf16* oph = (bf16*)p;  p += n4 * 2;
    bf16* opl = (bf16*)p;  p += n4 * 2;
    bool pre = ((size_t)(p - (char*)d_ws) <= ws_size);

    // regA: h1hi/h1lo -> cchi/cclo -> act (compact 8192 x FF bf16)
    bf16* h1hi = (bf16*)regA;
    bf16* h1lo = (bf16*)(regA + (size_t)T_ * D_ * 2);
    bf16* cchi = h1hi;
    bf16* cclo = h1lo;
    bf16* act  = (bf16*)regA;
    // regB: bcx (f32, 24 MB) -> y f32 [0:8) + h2 f32 [8:16) + h2b bf16 [16:20)
    float* bcx = (float*)regB;
    float* y   = (float*)regB;
    float* h2  = (float*)(regB + (size_t)T_ * D_ * 4);
    bf16*  h2b = (bf16*)(regB + (size_t)T_ * D_ * 8);

    float* out0 = (float*)d_out;                    // MoE output [T,D], f32 atomically accumulated
    float* res  = out0 + (size_t)T_ * D_;           // residual slot

    if (pre) {
        int nq = (int)((n1 + n2 + n3 + n4) / 4 / 256);   // 28672 blocks
        k_convert<<<nq, 256, 0, stream>>>(w1, w2, in_proj_w, out_proj_w,
                                          w1b, w2b, iph, ipl, oph, opl);
    }
    k_zero<<<(T_ * D_ + 255) / 256, 256, 0, stream>>>(out0);
    k_addnorm1<<<T_, 256, 0, stream>>>(hidden, residual, op_norm_w, h1hi, h1lo, res);
    if (pre)
        k_gemm_split2<<<dim3(3 * D_ / 128, T_ / 128), 256, 0, stream>>>(
            h1hi, h1lo, iph, ipl, bcx, T_, 3 * D_, D_);
    else
        k_gemm_split<<<dim3(3 * D_ / 128, T_ / 128), 256, 0, stream>>>(
            h1hi, h1lo, in_proj_w, bcx, T_, 3 * D_, D_);
    k_conv<<<T_, 256, 0, stream>>>(bcx, conv_w, cchi, cclo);
    if (pre)
        k_gemm_split2<<<dim3(D_ / 128, T_ / 128), 256, 0, stream>>>(
            cchi, cclo, oph, opl, y, T_, D_, D_);
    else
        k_gemm_split<<<dim3(D_ / 128, T_ / 128), 256, 0, stream>>>(
            cchi, cclo, out_proj_w, y, T_, D_, D_);
    k_addnorm2<<<T_, 256, 0, stream>>>(y, res, ffn_norm_w, h2, h2b);
    k_gate<<<T_, 256, 0, stream>>>(h2, gate_w, gate_bias, choice_idx, choice_wgt);
    k_scatter<<<E_, 256, 0, stream>>>(choice_idx, choice_wgt, cnt, tok_list, tok_w);
    k_scan<<<1, 64, 0, stream>>>(cnt, off);
    if (pre) {
        k_moe_w1_pre<<<dim3(FF_ / 64, E_ * (T_ / 128)), 256, 0, stream>>>(
            h2b, w1b, cnt, off, tok_list, act);
        k_moe_w2_pre<<<dim3(D_ / 128, E_ * (T_ / 128)), 256, 0, stream>>>(
            act, w2b, cnt, off, tok_list, tok_w, out0);
    } else {
        k_moe_w1<<<dim3(FF_ / 64, E_ * (T_ / 128)), 256, 0, stream>>>(
            h2b, w1, cnt, off, tok_list, act);
        k_moe_w2<<<dim3(D_ / 128, E_ * (T_ / 128)), 256, 0, stream>>>(
            act, w2, cnt, off, tok_list, tok_w, out0);
    }
}